// Round 14
// baseline (931.984 us; speedup 1.0000x reference)
//
#include <hip/hip_runtime.h>
#include <hip/hip_bf16.h>
#include <hip/hip_cooperative_groups.h>
#include <math.h>

namespace cg = cooperative_groups;

#define NN 100000   // nodes
#define EE 300000   // edges per type
#define TT 3        // edge types
#define LL 2        // layers
#define HH 128      // hidden
#define FF 5        // node feat
#define TE 64       // type embed
#define NT 200      // num ast types
#define BB 64       // graphs
#define NC 16       // pooling chunks per graph
#define CSRCAP 512  // per-type per-block LDS index cap (mean ~192)
#define WLSZ 131072 // per-layer fragment-packed weight size (shorts)
#define KIN 96      // padded K for input projection (69 -> 96)
#define IALD 104    // input-proj LDS row stride (shorts)
#define NBLK ((TT * NN + 1023) / 1024)   // 293 scan chunks

typedef short bf16x8 __attribute__((ext_vector_type(8)));
typedef float f32x4  __attribute__((ext_vector_type(4)));

__device__ __forceinline__ float bf2f(unsigned short u) {
    union { unsigned i; float f; } v; v.i = ((unsigned)u) << 16; return v.f;
}
__device__ __forceinline__ float bflo(unsigned u) {
    union { unsigned i; float f; } v; v.i = u << 16; return v.f;
}
__device__ __forceinline__ float bfhi(unsigned u) {
    union { unsigned i; float f; } v; v.i = u & 0xFFFF0000u; return v.f;
}
__device__ __forceinline__ unsigned short f2bf(float f) {
    union { float f; unsigned i; } v; v.f = f;
    unsigned b = v.i + (0x7FFFu + ((v.i >> 16) & 1u));   // RNE
    return (unsigned short)(b >> 16);
}
__device__ __forceinline__ unsigned pk2(float a, float b) {
    return (unsigned)f2bf(a) | ((unsigned)f2bf(b) << 16);
}
// split x ~= hi + lo (two bf16); hi+lo reproduces x to ~2^-16 rel
__device__ __forceinline__ void split_bf(float x, unsigned short& hi, unsigned short& lo) {
    hi = f2bf(x);
    lo = f2bf(x - bf2f(hi));
}

// ================================================================ cooperative prep:
// phase0: zero cnt + wprep(conv) + wprep(in) + blsum   (independent work)
// sync -> count -> sync -> chunk scans -> sync -> bsums scan -> sync ->
// offset add -> sync -> fill.   Bodies verbatim from validated R13 kernels.
__global__ __launch_bounds__(256) void prep_kernel(
    const int* __restrict__ ei,
    const float* __restrict__ W_l, const float* __restrict__ W_r,
    const float* __restrict__ b_l, const float* __restrict__ W_in,
    int* __restrict__ cnt, int* __restrict__ offs, int* __restrict__ cursor,
    int* __restrict__ csr, int* __restrict__ bsums,
    unsigned short* __restrict__ Wt16, unsigned short* __restrict__ Wp,
    float* __restrict__ blsum)
{
    cg::grid_group grid = cg::this_grid();
    const int tid = threadIdx.x;
    const int gtid = blockIdx.x * 256 + tid;
    const int gsz = gridDim.x * 256;
    const int M = TT * NN;
    __shared__ int wsum[4];
    __shared__ int sb[512];

    // ---- phase 0: zero cnt + weight prep
    for (int i = gtid; i < M; i += gsz) cnt[i] = 0;
    for (int i = gtid; i < LL * 4 * HH * HH; i += gsz) {
        int lm = i >> 14;
        int ck = i & 16383;
        int col = ck >> 7, k = ck & 127;
        int l = lm >> 2, m = lm & 3;
        float v;
        if (m == 0) {
            v = 0.f;
            for (int t = 0; t < TT; ++t)
                v += W_r[(((size_t)(l * TT + t)) << 14) + k * HH + col];
        } else {
            v = W_l[(((size_t)(l * TT + (m - 1))) << 14) + k * HH + col];
        }
        unsigned short hi, lo;
        split_bf(v, hi, lo);
        int cg2 = col >> 4, l15 = col & 15;
        int ks = k >> 5, lh = (k >> 3) & 3, j = k & 7;
        int lane = lh * 16 + l15;
        size_t base = (size_t)l * WLSZ;
        int Phi = (m * 2 + 0) * 4 + ks;
        int Plo = Phi + 4;
        Wt16[base + (size_t)Phi * 4096 + cg2 * 512 + lane * 8 + j] = hi;
        Wt16[base + (size_t)Plo * 4096 + cg2 * 512 + lane * 8 + j] = lo;
    }
    for (int i = gtid; i < KIN * HH; i += gsz) {
        int col = i & 127, k = i >> 7;
        float v = (k < TE + FF) ? W_in[k * HH + col] : 0.f;
        unsigned short hi, lo;
        split_bf(v, hi, lo);
        int cg2 = col >> 4, l15 = col & 15;
        int ks = k >> 5, lh = (k >> 3) & 3, j = k & 7;
        int lane = lh * 16 + l15;
        Wp[(size_t)ks * 4096 + cg2 * 512 + lane * 8 + j]       = hi;
        Wp[(size_t)(4 + ks) * 4096 + cg2 * 512 + lane * 8 + j] = lo;
    }
    for (int i = gtid; i < LL * HH; i += gsz) {
        int l = i >> 7, j = i & 127;
        float s = 0.f;
        for (int t = 0; t < TT; ++t) s += b_l[(l * TT + t) * HH + j];
        blsum[i] = s;
    }
    grid.sync();

    // ---- phase 1: count
    for (int i = gtid; i < TT * EE; i += gsz) {
        int t = i / EE, e = i - t * EE;
        int dst = ei[(t * 2 + 1) * EE + e];
        atomicAdd(&cnt[t * NN + dst], 1);
    }
    grid.sync();

    // ---- phase 2: per-chunk local exclusive scan (scan1 body)
    if (blockIdx.x < NBLK) {
        int base = blockIdx.x * 1024 + tid * 4;
        int a0 = 0, a1 = 0, a2 = 0, a3 = 0;
        if (base + 3 < M) { int4 v = *(const int4*)&cnt[base]; a0 = v.x; a1 = v.y; a2 = v.z; a3 = v.w; }
        else {
            if (base + 0 < M) a0 = cnt[base + 0];
            if (base + 1 < M) a1 = cnt[base + 1];
            if (base + 2 < M) a2 = cnt[base + 2];
            if (base + 3 < M) a3 = cnt[base + 3];
        }
        int s = a0 + a1 + a2 + a3;
        int lane = tid & 63, wv = tid >> 6;
        int x = s;
        #pragma unroll
        for (int o = 1; o < 64; o <<= 1) { int y = __shfl_up(x, o); if (lane >= o) x += y; }
        if (lane == 63) wsum[wv] = x;
        __syncthreads();
        int add = 0;
        for (int w = 0; w < wv; ++w) add += wsum[w];
        int incl = x + add;
        int e0 = incl - s, e1 = e0 + a0, e2 = e1 + a1, e3 = e2 + a2;
        if (base + 0 < M) offs[base + 0] = e0;
        if (base + 1 < M) offs[base + 1] = e1;
        if (base + 2 < M) offs[base + 2] = e2;
        if (base + 3 < M) offs[base + 3] = e3;
        if (tid == 255) bsums[blockIdx.x] = incl;
    }
    grid.sync();

    // ---- phase 3: scan bsums (block 0, Hillis-Steele over 512)
    if (blockIdx.x == 0) {
        sb[tid]       = (tid < NBLK) ? bsums[tid] : 0;
        sb[tid + 256] = (tid + 256 < NBLK) ? bsums[tid + 256] : 0;
        __syncthreads();
        for (int o = 1; o < 512; o <<= 1) {
            int v1 = sb[tid], v2 = sb[tid + 256];
            int a1 = (tid >= o) ? sb[tid - o] : 0;
            int a2 = (tid + 256 >= o) ? sb[tid + 256 - o] : 0;
            __syncthreads();
            sb[tid] = v1 + a1;
            sb[tid + 256] = v2 + a2;
            __syncthreads();
        }
        if (tid < NBLK) bsums[tid] = (tid == 0) ? 0 : sb[tid - 1];
        if (tid + 256 < NBLK) bsums[tid + 256] = sb[tid + 255];
    }
    grid.sync();

    // ---- phase 4: add chunk offsets, init cursor
    for (int i = gtid; i < M; i += gsz) {
        int v = offs[i] + bsums[i >> 10];
        offs[i] = v;
        cursor[i] = v;
    }
    grid.sync();

    // ---- phase 5: fill
    for (int i = gtid; i < TT * EE; i += gsz) {
        int t = i / EE, e = i - t * EE;
        int src = ei[(t * 2 + 0) * EE + e];
        int dst = ei[(t * 2 + 1) * EE + e];
        int pos = atomicAdd(&cursor[t * NN + dst], 1);
        csr[pos] = src;
    }
}

// ================================================================ input projection (split-bf16 MFMA, validated R11)
__global__ __launch_bounds__(512) void input_proj_kernel(
    const float* __restrict__ x, const int* __restrict__ ast,
    const float* __restrict__ emb, const unsigned short* __restrict__ Wp,
    const float* __restrict__ b_in, unsigned short* __restrict__ h16)
{
    __shared__ unsigned short Ahi[64 * IALD];   // 13.3 KB
    __shared__ unsigned short Alo[64 * IALD];   // 13.3 KB

    int tid = threadIdx.x;
    int row0 = blockIdx.x * 64;
    int w = tid >> 6, l = tid & 63;
    int l15 = l & 15, koff = (l >> 4) * 8;

    // ---- stage A-tile: 8 threads x 12 cols per row (96 cols)
    {
        int r = tid >> 3, sub = tid & 7;
        int gr = row0 + r;
        float v[12];
        #pragma unroll
        for (int j = 0; j < 12; ++j) v[j] = 0.f;
        if (gr < NN) {
            int a = ast[gr];
            #pragma unroll
            for (int j = 0; j < 12; ++j) {
                int k = sub * 12 + j;
                if (k < TE) v[j] = emb[a * TE + k];
                else if (k < TE + FF) v[j] = x[gr * FF + (k - TE)];
            }
        }
        unsigned short hs[12], ls[12];
        #pragma unroll
        for (int j = 0; j < 12; ++j) split_bf(v[j], hs[j], ls[j]);
        unsigned uh[6], ul[6];
        #pragma unroll
        for (int q = 0; q < 6; ++q) {
            uh[q] = (unsigned)hs[2 * q] | ((unsigned)hs[2 * q + 1] << 16);
            ul[q] = (unsigned)ls[2 * q] | ((unsigned)ls[2 * q + 1] << 16);
        }
        int base = r * IALD + sub * 12;
        uint2 h0; h0.x = uh[0]; h0.y = uh[1];
        uint2 h1; h1.x = uh[2]; h1.y = uh[3];
        uint2 h2; h2.x = uh[4]; h2.y = uh[5];
        uint2 l0; l0.x = ul[0]; l0.y = ul[1];
        uint2 l1; l1.x = ul[2]; l1.y = ul[3];
        uint2 l2; l2.x = ul[4]; l2.y = ul[5];
        *(uint2*)&Ahi[base + 0] = h0;
        *(uint2*)&Ahi[base + 4] = h1;
        *(uint2*)&Ahi[base + 8] = h2;
        *(uint2*)&Alo[base + 0] = l0;
        *(uint2*)&Alo[base + 4] = l1;
        *(uint2*)&Alo[base + 8] = l2;
    }
    __syncthreads();

    // ---- MFMA: 3 k-steps, W fragments direct from L2-hot pack
    f32x4 acc[4] = {};
    #pragma unroll
    for (int ks = 0; ks < 3; ++ks) {
        bf16x8 wh = *(const bf16x8*)&Wp[(size_t)ks * 4096 + w * 512 + l * 8];
        bf16x8 wl = *(const bf16x8*)&Wp[(size_t)(4 + ks) * 4096 + w * 512 + l * 8];
        int k0 = ks * 32 + koff;
        #pragma unroll
        for (int rt = 0; rt < 4; ++rt) {
            bf16x8 ah = *(const bf16x8*)&Ahi[(rt * 16 + l15) * IALD + k0];
            bf16x8 al = *(const bf16x8*)&Alo[(rt * 16 + l15) * IALD + k0];
            acc[rt] = __builtin_amdgcn_mfma_f32_16x16x32_bf16(ah, wh, acc[rt], 0, 0, 0);
            acc[rt] = __builtin_amdgcn_mfma_f32_16x16x32_bf16(al, wh, acc[rt], 0, 0, 0);
            acc[rt] = __builtin_amdgcn_mfma_f32_16x16x32_bf16(ah, wl, acc[rt], 0, 0, 0);
        }
    }

    // ---- bias + bf16 store (m89 C/D layout, validated epilogue pattern)
    {
        int col = w * 16 + l15;
        float bv = b_in[col];
        int rbase = row0 + (l >> 4) * 4;
        #pragma unroll
        for (int rt = 0; rt < 4; ++rt) {
            #pragma unroll
            for (int i = 0; i < 4; ++i) {
                int grr = rbase + rt * 16 + i;
                if (grr < NN) h16[(size_t)grr * HH + col] = f2bf(acc[rt][i] + bv);
            }
        }
    }
}

// ================================================================ conv layer + fused LayerNorm (validated R13, verbatim)
#define ALD 136   // padded LDS stride (shorts): 272 B -> 2-way bank aliasing (free)
#define LNLD 132  // f32 LN buffer row stride

__global__ __launch_bounds__(512) void conv_kernel(
    const unsigned short* __restrict__ h16,      // [N][128] bf16 (dense A + gather)
    const unsigned short* __restrict__ Wt_l,     // fragment-packed, per-layer base
    const float* __restrict__ blsum_l,
    const float* __restrict__ gamma, const float* __restrict__ beta,
    const int* __restrict__ offs, const int* __restrict__ cnt, const int* __restrict__ csr,
    unsigned short* __restrict__ hout16)
{
    __shared__ char smem[64 * LNLD * 4];         // 33.8 KB (Ln overlays Ahi+csr)
    unsigned short* Ahi = (unsigned short*)smem;             // 17.4 KB
    int* csr_lds = (int*)(smem + 64 * ALD * 2);              // 6 KB  [TT][CSRCAP]
    float* Ln = (float*)smem;                                // 33.8 KB (reused at end)
    __shared__ int base_lds[TT], len_lds[TT], flag_lds[TT];

    int tid = threadIdx.x;
    int row0 = blockIdx.x * 64;
    int nrow = min(64, NN - row0);
    int w = tid >> 6, l = tid & 63;
    int l15 = l & 15, koff = (l >> 4) * 8;

    // ---- stage CSR ranges (rows consecutive -> contiguous csr slice per type)
    if (tid < TT) {
        int t = tid;
        int last = row0 + nrow - 1;
        int b = offs[t * NN + row0];
        int e = offs[t * NN + last] + cnt[t * NN + last];
        base_lds[t] = b;
        len_lds[t] = e - b;
        flag_lds[t] = (e - b) <= CSRCAP;
    }
    __syncthreads();
    #pragma unroll
    for (int t = 0; t < TT; ++t) {
        if (flag_lds[t]) {
            int b = base_lds[t], len = len_lds[t];
            for (int i = tid; i < len; i += 512) csr_lds[t * CSRCAP + i] = csr[b + i];
        }
    }
    __syncthreads();

    int r = tid >> 3, sub = tid & 7;
    int gr = row0 + r;

    f32x4 acc[4] = {};

    #pragma unroll
    for (int m = 0; m < 4; ++m) {
        // ---- stage A-tile (single bf16 plane)
        if (m == 0) {
            #pragma unroll
            for (int s2 = 0; s2 < 2; ++s2) {
                int c16 = s2 * 512 + tid;
                int rr = c16 >> 4, k0 = (c16 & 15) * 8;
                int grr = row0 + rr;
                uint4 hv = {0u, 0u, 0u, 0u};
                if (grr < NN) hv = *(const uint4*)&h16[(size_t)grr * 128 + k0];
                *(uint4*)&Ahi[rr * ALD + k0] = hv;
            }
        } else {
            int t = m - 1;   // static under #pragma unroll
            float ms[16];
            #pragma unroll
            for (int j = 0; j < 16; ++j) ms[j] = 0.f;
            float inv = 0.f;
            if (gr < NN) {
                int o = offs[t * NN + gr];
                int c = cnt[t * NN + gr];
                inv = (c > 0) ? 1.0f / (float)c : 0.0f;
                bool inl = flag_lds[t] != 0;
                int rel = o - base_lds[t];
                const unsigned* h16u = (const unsigned*)h16;
                for (int j = 0; j < c; ++j) {
                    int src = inl ? csr_lds[t * CSRCAP + rel + j] : csr[o + j];
                    const uint4* hp = (const uint4*)&h16u[(size_t)src * 64 + sub * 8];
                    uint4 v0 = hp[0], v1 = hp[1];
                    ms[0]  += bflo(v0.x); ms[1]  += bfhi(v0.x);
                    ms[2]  += bflo(v0.y); ms[3]  += bfhi(v0.y);
                    ms[4]  += bflo(v0.z); ms[5]  += bfhi(v0.z);
                    ms[6]  += bflo(v0.w); ms[7]  += bfhi(v0.w);
                    ms[8]  += bflo(v1.x); ms[9]  += bfhi(v1.x);
                    ms[10] += bflo(v1.y); ms[11] += bfhi(v1.y);
                    ms[12] += bflo(v1.z); ms[13] += bfhi(v1.z);
                    ms[14] += bflo(v1.w); ms[15] += bfhi(v1.w);
                }
            }
            uint4 hv0, hv1;
            hv0.x = pk2(ms[0] * inv,  ms[1] * inv);
            hv0.y = pk2(ms[2] * inv,  ms[3] * inv);
            hv0.z = pk2(ms[4] * inv,  ms[5] * inv);
            hv0.w = pk2(ms[6] * inv,  ms[7] * inv);
            hv1.x = pk2(ms[8] * inv,  ms[9] * inv);
            hv1.y = pk2(ms[10] * inv, ms[11] * inv);
            hv1.z = pk2(ms[12] * inv, ms[13] * inv);
            hv1.w = pk2(ms[14] * inv, ms[15] * inv);
            *(uint4*)&Ahi[r * ALD + sub * 16]     = hv0;
            *(uint4*)&Ahi[r * ALD + sub * 16 + 8] = hv1;
        }
        __syncthreads();
        // ---- MFMA: A single-plane x W split (wh + wl), W direct from L2-hot pack
        #pragma unroll
        for (int ks = 0; ks < 4; ++ks) {
            bf16x8 wh = *(const bf16x8*)&Wt_l[(size_t)(8 * m + ks) * 4096 + w * 512 + l * 8];
            bf16x8 wl = *(const bf16x8*)&Wt_l[(size_t)(8 * m + 4 + ks) * 4096 + w * 512 + l * 8];
            int k0 = ks * 32 + koff;
            #pragma unroll
            for (int rt = 0; rt < 4; ++rt) {
                bf16x8 ah = *(const bf16x8*)&Ahi[(rt * 16 + l15) * ALD + k0];
                acc[rt] = __builtin_amdgcn_mfma_f32_16x16x32_bf16(ah, wh, acc[rt], 0, 0, 0);
                acc[rt] = __builtin_amdgcn_mfma_f32_16x16x32_bf16(ah, wl, acc[rt], 0, 0, 0);
            }
        }
        __syncthreads();   // before next m overwrites A (also frees LDS for Ln)
    }

    // ---- dump acc+bias to f32 LDS [64][132]
    {
        int col = w * 16 + l15;
        float bv = blsum_l[col];
        int rloc = (l >> 4) * 4;
        #pragma unroll
        for (int rt = 0; rt < 4; ++rt) {
            #pragma unroll
            for (int i = 0; i < 4; ++i) {
                Ln[(rloc + rt * 16 + i) * LNLD + col] = acc[rt][i] + bv;
            }
        }
    }
    __syncthreads();
    // ---- fused LayerNorm: 8 threads/row, shfl_xor reduce, bf16 write
    {
        const float* Lr = Ln + r * LNLD + sub * 16;
        float4 v0 = *(const float4*)(Lr + 0);
        float4 v1 = *(const float4*)(Lr + 4);
        float4 v2 = *(const float4*)(Lr + 8);
        float4 v3 = *(const float4*)(Lr + 12);
        float s = v0.x + v0.y + v0.z + v0.w + v1.x + v1.y + v1.z + v1.w
                + v2.x + v2.y + v2.z + v2.w + v3.x + v3.y + v3.z + v3.w;
        float q = v0.x*v0.x + v0.y*v0.y + v0.z*v0.z + v0.w*v0.w
                + v1.x*v1.x + v1.y*v1.y + v1.z*v1.z + v1.w*v1.w
                + v2.x*v2.x + v2.y*v2.y + v2.z*v2.z + v2.w*v2.w
                + v3.x*v3.x + v3.y*v3.y + v3.z*v3.z + v3.w*v3.w;
        #pragma unroll
        for (int o = 1; o < 8; o <<= 1) { s += __shfl_xor(s, o); q += __shfl_xor(q, o); }
        float mu = s * (1.0f / HH);
        float var = q * (1.0f / HH) - mu * mu;
        float rs = rsqrtf(var + 1e-5f);
        if (gr < NN) {
            const float4* g4 = (const float4*)(gamma + sub * 16);
            const float4* b4 = (const float4*)(beta + sub * 16);
            float4 g0 = g4[0], g1 = g4[1], g2 = g4[2], g3 = g4[3];
            float4 e0 = b4[0], e1 = b4[1], e2 = b4[2], e3 = b4[3];
            uint4 o0, o1;
            o0.x = pk2((v0.x - mu) * rs * g0.x + e0.x, (v0.y - mu) * rs * g0.y + e0.y);
            o0.y = pk2((v0.z - mu) * rs * g0.z + e0.z, (v0.w - mu) * rs * g0.w + e0.w);
            o0.z = pk2((v1.x - mu) * rs * g1.x + e1.x, (v1.y - mu) * rs * g1.y + e1.y);
            o0.w = pk2((v1.z - mu) * rs * g1.z + e1.z, (v1.w - mu) * rs * g1.w + e1.w);
            o1.x = pk2((v2.x - mu) * rs * g2.x + e2.x, (v2.y - mu) * rs * g2.y + e2.y);
            o1.y = pk2((v2.z - mu) * rs * g2.z + e2.z, (v2.w - mu) * rs * g2.w + e2.w);
            o1.z = pk2((v3.x - mu) * rs * g3.x + e3.x, (v3.y - mu) * rs * g3.y + e3.y);
            o1.w = pk2((v3.z - mu) * rs * g3.z + e3.z, (v3.w - mu) * rs * g3.w + e3.w);
            uint4* op = (uint4*)&hout16[(size_t)gr * 128 + sub * 16];
            op[0] = o0; op[1] = o1;
        }
    }
}

// ================================================================ cooperative pooling (pool1 + pool2 fused)
__global__ __launch_bounds__(256) void pool_kernel(
    const unsigned short* __restrict__ h16, const int* __restrict__ batch,
    float* __restrict__ psum, float* __restrict__ pmax, float* __restrict__ out)
{
    cg::grid_group grid = cg::this_grid();
    // ---- phase 1: per-chunk partials (pool1 body, validated R10)
    {
        int g = blockIdx.x >> 4, c = blockIdx.x & (NC - 1);
        int start, end;
        {
            int lo = 0, hi = NN;
            while (lo < hi) { int mid = (lo + hi) >> 1; if (batch[mid] < g) lo = mid + 1; else hi = mid; }
            start = lo;
            hi = NN;
            while (lo < hi) { int mid = (lo + hi) >> 1; if (batch[mid] < g + 1) lo = mid + 1; else hi = mid; }
            end = lo;
        }
        int len = end - start;
        int chunk = (len + NC - 1) / NC;
        int clo = start + c * chunk;
        int chi = min(clo + chunk, end);
        int tid = threadIdx.x;
        int d = tid & 127, half = tid >> 7;
        float s = 0.f, m = -INFINITY;
        for (int n = clo + half; n < chi; n += 2) {
            float v = bf2f(h16[(size_t)n * HH + d]);
            s += v; m = fmaxf(m, v);
        }
        __shared__ float ss[256], sm[256];
        ss[tid] = s; sm[tid] = m;
        __syncthreads();
        if (half == 0) {
            s += ss[tid + 128];
            m = fmaxf(m, sm[tid + 128]);
            psum[(size_t)blockIdx.x * HH + d] = s;
            pmax[(size_t)blockIdx.x * HH + d] = m;
        }
    }
    grid.sync();
    // ---- phase 2: fold (pool2 body, blocks 0..BB-1, threads 0..HH-1)
    if (blockIdx.x < BB && threadIdx.x < HH) {
        int g = blockIdx.x;
        int d = threadIdx.x;
        int start, end;
        {
            int lo = 0, hi = NN;
            while (lo < hi) { int mid = (lo + hi) >> 1; if (batch[mid] < g) lo = mid + 1; else hi = mid; }
            start = lo;
            hi = NN;
            while (lo < hi) { int mid = (lo + hi) >> 1; if (batch[mid] < g + 1) lo = mid + 1; else hi = mid; }
            end = lo;
        }
        float s = 0.f, m = -INFINITY;
        #pragma unroll
        for (int c = 0; c < NC; ++c) {
            s += psum[(size_t)(g * NC + c) * HH + d];
            m = fmaxf(m, pmax[(size_t)(g * NC + c) * HH + d]);
        }
        int cg2 = end - start;
        out[g * 2 * HH + d] = s / fmaxf((float)cg2, 1.0f);
        out[g * 2 * HH + HH + d] = (cg2 > 0) ? m : 0.0f;
    }
}

// ================================================================ launch
extern "C" void kernel_launch(void* const* d_in, const int* in_sizes, int n_in,
                              void* d_out, int out_size, void* d_ws, size_t ws_size,
                              hipStream_t stream) {
    const float* x     = (const float*)d_in[0];
    const int*   ast   = (const int*)d_in[1];
    const int*   batch = (const int*)d_in[2];
    const int*   ei    = (const int*)d_in[3];
    const float* emb   = (const float*)d_in[4];
    const float* W_in  = (const float*)d_in[5];
    const float* b_in  = (const float*)d_in[6];
    const float* W_l   = (const float*)d_in[7];
    const float* b_l   = (const float*)d_in[8];
    const float* W_r   = (const float*)d_in[9];
    const float* gamma = (const float*)d_in[10];
    const float* beta  = (const float*)d_in[11];
    float* out = (float*)d_out;

    const int M = TT * NN;

    char* p = (char*)d_ws;
    unsigned short* h16a = (unsigned short*)p;  p += (size_t)NN * HH * 2;   // 25.6 MB
    unsigned short* h16b = (unsigned short*)p;  p += (size_t)NN * HH * 2;   // 25.6 MB
    unsigned short* Wt16 = (unsigned short*)p;  p += (size_t)LL * WLSZ * 2;
    unsigned short* Wp_in = (unsigned short*)p; p += (size_t)32768 * 2;     // 64 KB
    float* blsum = (float*)p;                   p += LL * HH * 4;
    float* psum = (float*)p;                    p += (size_t)BB * NC * HH * 4;
    float* pmax = (float*)p;                    p += (size_t)BB * NC * HH * 4;
    int* cnt    = (int*)p;                      p += (size_t)M * 4;
    int* offs   = (int*)p;                      p += (size_t)M * 4;
    int* cursor = (int*)p;                      p += (size_t)M * 4;
    int* csr    = (int*)p;                      p += (size_t)TT * EE * 4;
    int* bsums  = (int*)p;

    // single cooperative prep: zero + wprep + count + scan + fill
    {
        void* args[] = {(void*)&ei, (void*)&W_l, (void*)&W_r, (void*)&b_l, (void*)&W_in,
                        (void*)&cnt, (void*)&offs, (void*)&cursor, (void*)&csr, (void*)&bsums,
                        (void*)&Wt16, (void*)&Wp_in, (void*)&blsum};
        hipLaunchCooperativeKernel((void*)prep_kernel, dim3(1024), dim3(256), args, 0, stream);
    }

    int conv_grid = (NN + 63) / 64;
    input_proj_kernel<<<conv_grid, 512, 0, stream>>>(x, ast, emb, Wp_in, b_in, h16a);
    // layer 0: h16a -> h16b (conv + fused LN)
    conv_kernel<<<conv_grid, 512, 0, stream>>>(h16a, Wt16, blsum, gamma, beta,
                                               offs, cnt, csr, h16b);
    // layer 1: h16b -> h16a (conv + fused LN)
    conv_kernel<<<conv_grid, 512, 0, stream>>>(h16b, Wt16 + (size_t)WLSZ, blsum + HH,
                                               gamma + HH, beta + HH,
                                               offs, cnt, csr, h16a);
    // cooperative pooling (pool1 + pool2)
    {
        void* args[] = {(void*)&h16a, (void*)&batch, (void*)&psum, (void*)&pmax, (void*)&out};
        hipLaunchCooperativeKernel((void*)pool_kernel, dim3(BB * NC), dim3(256), args, 0, stream);
    }
}

// Round 15
// 308.495 us; speedup vs baseline: 3.0211x; 3.0211x over previous
//
#include <hip/hip_runtime.h>
#include <hip/hip_bf16.h>
#include <math.h>

#define NN 100000   // nodes
#define EE 300000   // edges per type
#define TT 3        // edge types
#define LL 2        // layers
#define HH 128      // hidden
#define FF 5        // node feat
#define TE 64       // type embed
#define NT 200      // num ast types
#define BB 64       // graphs
#define CSRCAP 512  // per-type per-block LDS index cap (mean ~192)
#define WLSZ 131072 // per-layer fragment-packed weight size (shorts)
#define KIN 96      // padded K for input projection (69 -> 96)
#define IALD 104    // input-proj LDS row stride (shorts)

typedef short bf16x8 __attribute__((ext_vector_type(8)));
typedef float f32x4  __attribute__((ext_vector_type(4)));

__device__ __forceinline__ float bf2f(unsigned short u) {
    union { unsigned i; float f; } v; v.i = ((unsigned)u) << 16; return v.f;
}
__device__ __forceinline__ float bflo(unsigned u) {
    union { unsigned i; float f; } v; v.i = u << 16; return v.f;
}
__device__ __forceinline__ float bfhi(unsigned u) {
    union { unsigned i; float f; } v; v.i = u & 0xFFFF0000u; return v.f;
}
__device__ __forceinline__ unsigned short f2bf(float f) {
    union { float f; unsigned i; } v; v.f = f;
    unsigned b = v.i + (0x7FFFu + ((v.i >> 16) & 1u));   // RNE
    return (unsigned short)(b >> 16);
}
__device__ __forceinline__ unsigned pk2(float a, float b) {
    return (unsigned)f2bf(a) | ((unsigned)f2bf(b) << 16);
}
__device__ __forceinline__ void split_bf(float x, unsigned short& hi, unsigned short& lo) {
    hi = f2bf(x);
    lo = f2bf(x - bf2f(hi));
}
// monotone f32 <-> u32 encoding for atomicMax
__device__ __forceinline__ unsigned fenc(float f) {
    union { float f; unsigned u; } v; v.f = f;
    return (v.u & 0x80000000u) ? ~v.u : (v.u | 0x80000000u);
}
__device__ __forceinline__ float fdec(unsigned key) {
    union { float f; unsigned u; } v;
    v.u = (key & 0x80000000u) ? (key ^ 0x80000000u) : ~key;
    return v.f;
}
#define PMAX_INIT 0x007FFFFFu   // fenc(-inf)

// ================================================================ scan kernels (validated R2/R13)
__global__ __launch_bounds__(256) void scan1_kernel(const int* __restrict__ cnt,
                                                    int* __restrict__ offs,
                                                    int* __restrict__ bsums, int M) {
    int tid = threadIdx.x;
    int base = blockIdx.x * 1024 + tid * 4;
    int a0 = 0, a1 = 0, a2 = 0, a3 = 0;
    if (base + 3 < M) { int4 v = *(const int4*)&cnt[base]; a0 = v.x; a1 = v.y; a2 = v.z; a3 = v.w; }
    else {
        if (base + 0 < M) a0 = cnt[base + 0];
        if (base + 1 < M) a1 = cnt[base + 1];
        if (base + 2 < M) a2 = cnt[base + 2];
        if (base + 3 < M) a3 = cnt[base + 3];
    }
    int s = a0 + a1 + a2 + a3;
    int lane = tid & 63, wv = tid >> 6;
    int x = s;
    #pragma unroll
    for (int o = 1; o < 64; o <<= 1) { int y = __shfl_up(x, o); if (lane >= o) x += y; }
    __shared__ int wsum[4];
    if (lane == 63) wsum[wv] = x;
    __syncthreads();
    int add = 0;
    for (int w = 0; w < wv; ++w) add += wsum[w];
    int incl = x + add;
    int e0 = incl - s, e1 = e0 + a0, e2 = e1 + a1, e3 = e2 + a2;
    if (base + 0 < M) offs[base + 0] = e0;
    if (base + 1 < M) offs[base + 1] = e1;
    if (base + 2 < M) offs[base + 2] = e2;
    if (base + 3 < M) offs[base + 3] = e3;
    if (tid == 255) bsums[blockIdx.x] = incl;
}

__global__ __launch_bounds__(512) void scan2_kernel(int* __restrict__ bsums, int NB) {
    int tid = threadIdx.x;
    int s = (tid < NB) ? bsums[tid] : 0;
    int lane = tid & 63, wv = tid >> 6;
    int x = s;
    #pragma unroll
    for (int o = 1; o < 64; o <<= 1) { int y = __shfl_up(x, o); if (lane >= o) x += y; }
    __shared__ int wsum[8];
    if (lane == 63) wsum[wv] = x;
    __syncthreads();
    int add = 0;
    for (int w = 0; w < wv; ++w) add += wsum[w];
    if (tid < NB) bsums[tid] = x + add - s;
}

__global__ void scan3_kernel(int* __restrict__ offs, const int* __restrict__ bsums,
                             int* __restrict__ cursor, int M) {
    int i = blockIdx.x * 256 + threadIdx.x;
    if (i >= M) return;
    int v = offs[i] + bsums[i >> 10];
    offs[i] = v;
    cursor[i] = v;
}

__global__ void fill_kernel(const int* __restrict__ ei, int* __restrict__ cursor,
                            int* __restrict__ csr) {
    int i = blockIdx.x * blockDim.x + threadIdx.x;
    if (i >= TT * EE) return;
    int t = i / EE, e = i - t * EE;
    int src = ei[(t * 2 + 0) * EE + e];
    int dst = ei[(t * 2 + 1) * EE + e];
    int pos = atomicAdd(&cursor[t * NN + dst], 1);
    csr[pos] = src;
}

// ================================================================ weight prep (+ psum/pmax init)
__global__ void wprep_kernel(const float* __restrict__ W_l, const float* __restrict__ W_r,
                             const float* __restrict__ b_l, const float* __restrict__ W_in,
                             unsigned short* __restrict__ Wt16, unsigned short* __restrict__ Wp,
                             float* __restrict__ blsum,
                             float* __restrict__ psum, unsigned* __restrict__ pmaxu) {
    int i = blockIdx.x * 256 + threadIdx.x;
    if (i < LL * 4 * HH * HH) {
        int lm = i >> 14;
        int ck = i & 16383;
        int col = ck >> 7, k = ck & 127;
        int l = lm >> 2, m = lm & 3;
        float v;
        if (m == 0) {
            v = 0.f;
            for (int t = 0; t < TT; ++t)
                v += W_r[(((size_t)(l * TT + t)) << 14) + k * HH + col];
        } else {
            v = W_l[(((size_t)(l * TT + (m - 1))) << 14) + k * HH + col];
        }
        unsigned short hi, lo;
        split_bf(v, hi, lo);
        int cg = col >> 4, l15 = col & 15;
        int ks = k >> 5, lh = (k >> 3) & 3, j = k & 7;
        int lane = lh * 16 + l15;
        size_t base = (size_t)l * WLSZ;
        int Phi = (m * 2 + 0) * 4 + ks;
        int Plo = Phi + 4;
        Wt16[base + (size_t)Phi * 4096 + cg * 512 + lane * 8 + j] = hi;
        Wt16[base + (size_t)Plo * 4096 + cg * 512 + lane * 8 + j] = lo;
    }
    if (i < KIN * HH) {
        int col = i & 127, k = i >> 7;
        float v = (k < TE + FF) ? W_in[k * HH + col] : 0.f;
        unsigned short hi, lo;
        split_bf(v, hi, lo);
        int cg = col >> 4, l15 = col & 15;
        int ks = k >> 5, lh = (k >> 3) & 3, j = k & 7;
        int lane = lh * 16 + l15;
        Wp[(size_t)ks * 4096 + cg * 512 + lane * 8 + j]       = hi;
        Wp[(size_t)(4 + ks) * 4096 + cg * 512 + lane * 8 + j] = lo;
    }
    if (i < LL * HH) {
        int l = i >> 7, j = i & 127;
        float s = 0.f;
        for (int t = 0; t < TT; ++t) s += b_l[(l * TT + t) * HH + j];
        blsum[i] = s;
    }
    if (i < BB * HH) {
        psum[i] = 0.f;
        pmaxu[i] = PMAX_INIT;
    }
}

// ================================================================ input projection + fused edge count
__global__ __launch_bounds__(512) void input_proj_kernel(
    const float* __restrict__ x, const int* __restrict__ ast,
    const float* __restrict__ emb, const unsigned short* __restrict__ Wp,
    const float* __restrict__ b_in, unsigned short* __restrict__ h16,
    const int* __restrict__ ei, int* __restrict__ cnt)
{
    __shared__ unsigned short Ahi[64 * IALD];   // 13.3 KB
    __shared__ unsigned short Alo[64 * IALD];   // 13.3 KB

    int tid = threadIdx.x;
    int row0 = blockIdx.x * 64;
    int w = tid >> 6, l = tid & 63;
    int l15 = l & 15, koff = (l >> 4) * 8;

    // ---- fused count (grid-stride over all edges; completes by kernel end)
    {
        int gsz = gridDim.x * 512;
        for (int i = blockIdx.x * 512 + tid; i < TT * EE; i += gsz) {
            int t = i / EE, e = i - t * EE;
            atomicAdd(&cnt[t * NN + ei[(t * 2 + 1) * EE + e]], 1);
        }
    }

    // ---- stage A-tile: 8 threads x 12 cols per row (96 cols)
    {
        int r = tid >> 3, sub = tid & 7;
        int gr = row0 + r;
        float v[12];
        #pragma unroll
        for (int j = 0; j < 12; ++j) v[j] = 0.f;
        if (gr < NN) {
            int a = ast[gr];
            #pragma unroll
            for (int j = 0; j < 12; ++j) {
                int k = sub * 12 + j;
                if (k < TE) v[j] = emb[a * TE + k];
                else if (k < TE + FF) v[j] = x[gr * FF + (k - TE)];
            }
        }
        unsigned short hs[12], ls[12];
        #pragma unroll
        for (int j = 0; j < 12; ++j) split_bf(v[j], hs[j], ls[j]);
        unsigned uh[6], ul[6];
        #pragma unroll
        for (int q = 0; q < 6; ++q) {
            uh[q] = (unsigned)hs[2 * q] | ((unsigned)hs[2 * q + 1] << 16);
            ul[q] = (unsigned)ls[2 * q] | ((unsigned)ls[2 * q + 1] << 16);
        }
        int base = r * IALD + sub * 12;
        uint2 h0; h0.x = uh[0]; h0.y = uh[1];
        uint2 h1; h1.x = uh[2]; h1.y = uh[3];
        uint2 h2; h2.x = uh[4]; h2.y = uh[5];
        uint2 l0; l0.x = ul[0]; l0.y = ul[1];
        uint2 l1; l1.x = ul[2]; l1.y = ul[3];
        uint2 l2; l2.x = ul[4]; l2.y = ul[5];
        *(uint2*)&Ahi[base + 0] = h0;
        *(uint2*)&Ahi[base + 4] = h1;
        *(uint2*)&Ahi[base + 8] = h2;
        *(uint2*)&Alo[base + 0] = l0;
        *(uint2*)&Alo[base + 4] = l1;
        *(uint2*)&Alo[base + 8] = l2;
    }
    __syncthreads();

    // ---- MFMA: 3 k-steps
    f32x4 acc[4] = {};
    #pragma unroll
    for (int ks = 0; ks < 3; ++ks) {
        bf16x8 wh = *(const bf16x8*)&Wp[(size_t)ks * 4096 + w * 512 + l * 8];
        bf16x8 wl = *(const bf16x8*)&Wp[(size_t)(4 + ks) * 4096 + w * 512 + l * 8];
        int k0 = ks * 32 + koff;
        #pragma unroll
        for (int rt = 0; rt < 4; ++rt) {
            bf16x8 ah = *(const bf16x8*)&Ahi[(rt * 16 + l15) * IALD + k0];
            bf16x8 al = *(const bf16x8*)&Alo[(rt * 16 + l15) * IALD + k0];
            acc[rt] = __builtin_amdgcn_mfma_f32_16x16x32_bf16(ah, wh, acc[rt], 0, 0, 0);
            acc[rt] = __builtin_amdgcn_mfma_f32_16x16x32_bf16(al, wh, acc[rt], 0, 0, 0);
            acc[rt] = __builtin_amdgcn_mfma_f32_16x16x32_bf16(ah, wl, acc[rt], 0, 0, 0);
        }
    }

    // ---- bias + bf16 store (m89 C/D layout)
    {
        int col = w * 16 + l15;
        float bv = b_in[col];
        int rbase = row0 + (l >> 4) * 4;
        #pragma unroll
        for (int rt = 0; rt < 4; ++rt) {
            #pragma unroll
            for (int i = 0; i < 4; ++i) {
                int grr = rbase + rt * 16 + i;
                if (grr < NN) h16[(size_t)grr * HH + col] = f2bf(acc[rt][i] + bv);
            }
        }
    }
}

// ================================================================ conv layer + fused LN (+ optional fused pool partials)
#define ALD 136
#define LNLD 132

template<int DOPOOL>
__global__ __launch_bounds__(512) void conv_kernel(
    const unsigned short* __restrict__ h16,
    const unsigned short* __restrict__ Wt_l,
    const float* __restrict__ blsum_l,
    const float* __restrict__ gamma, const float* __restrict__ beta,
    const int* __restrict__ offs, const int* __restrict__ cnt, const int* __restrict__ csr,
    unsigned short* __restrict__ hout16,
    const int* __restrict__ batch, float* __restrict__ psum, unsigned* __restrict__ pmaxu)
{
    __shared__ char smem[64 * LNLD * 4];         // 33.8 KB (Ln overlays Ahi+csr)
    unsigned short* Ahi = (unsigned short*)smem;             // 17.4 KB
    int* csr_lds = (int*)(smem + 64 * ALD * 2);              // 6 KB  [TT][CSRCAP]
    float* Ln = (float*)smem;                                // 33.8 KB (reused at end)
    __shared__ int base_lds[TT], len_lds[TT], flag_lds[TT];
    __shared__ int gidx[64];
    __shared__ float qsum[4][HH], qmax[4][HH];               // 4 KB

    int tid = threadIdx.x;
    int row0 = blockIdx.x * 64;
    int nrow = min(64, NN - row0);
    int w = tid >> 6, l = tid & 63;
    int l15 = l & 15, koff = (l >> 4) * 8;

    if (tid < TT) {
        int t = tid;
        int last = row0 + nrow - 1;
        int b = offs[t * NN + row0];
        int e = offs[t * NN + last] + cnt[t * NN + last];
        base_lds[t] = b;
        len_lds[t] = e - b;
        flag_lds[t] = (e - b) <= CSRCAP;
    }
    if (DOPOOL && tid < 64) gidx[tid] = (row0 + tid < NN) ? batch[row0 + tid] : -1;
    __syncthreads();
    #pragma unroll
    for (int t = 0; t < TT; ++t) {
        if (flag_lds[t]) {
            int b = base_lds[t], len = len_lds[t];
            for (int i = tid; i < len; i += 512) csr_lds[t * CSRCAP + i] = csr[b + i];
        }
    }
    __syncthreads();

    int r = tid >> 3, sub = tid & 7;
    int gr = row0 + r;

    f32x4 acc[4] = {};

    #pragma unroll
    for (int m = 0; m < 4; ++m) {
        if (m == 0) {
            #pragma unroll
            for (int s2 = 0; s2 < 2; ++s2) {
                int c16 = s2 * 512 + tid;
                int rr = c16 >> 4, k0 = (c16 & 15) * 8;
                int grr = row0 + rr;
                uint4 hv = {0u, 0u, 0u, 0u};
                if (grr < NN) hv = *(const uint4*)&h16[(size_t)grr * 128 + k0];
                *(uint4*)&Ahi[rr * ALD + k0] = hv;
            }
        } else {
            int t = m - 1;
            float ms[16];
            #pragma unroll
            for (int j = 0; j < 16; ++j) ms[j] = 0.f;
            float inv = 0.f;
            if (gr < NN) {
                int o = offs[t * NN + gr];
                int c = cnt[t * NN + gr];
                inv = (c > 0) ? 1.0f / (float)c : 0.0f;
                bool inl = flag_lds[t] != 0;
                int rel = o - base_lds[t];
                const unsigned* h16u = (const unsigned*)h16;
                for (int j = 0; j < c; ++j) {
                    int src = inl ? csr_lds[t * CSRCAP + rel + j] : csr[o + j];
                    const uint4* hp = (const uint4*)&h16u[(size_t)src * 64 + sub * 8];
                    uint4 v0 = hp[0], v1 = hp[1];
                    ms[0]  += bflo(v0.x); ms[1]  += bfhi(v0.x);
                    ms[2]  += bflo(v0.y); ms[3]  += bfhi(v0.y);
                    ms[4]  += bflo(v0.z); ms[5]  += bfhi(v0.z);
                    ms[6]  += bflo(v0.w); ms[7]  += bfhi(v0.w);
                    ms[8]  += bflo(v1.x); ms[9]  += bfhi(v1.x);
                    ms[10] += bflo(v1.y); ms[11] += bfhi(v1.y);
                    ms[12] += bflo(v1.z); ms[13] += bfhi(v1.z);
                    ms[14] += bflo(v1.w); ms[15] += bfhi(v1.w);
                }
            }
            uint4 hv0, hv1;
            hv0.x = pk2(ms[0] * inv,  ms[1] * inv);
            hv0.y = pk2(ms[2] * inv,  ms[3] * inv);
            hv0.z = pk2(ms[4] * inv,  ms[5] * inv);
            hv0.w = pk2(ms[6] * inv,  ms[7] * inv);
            hv1.x = pk2(ms[8] * inv,  ms[9] * inv);
            hv1.y = pk2(ms[10] * inv, ms[11] * inv);
            hv1.z = pk2(ms[12] * inv, ms[13] * inv);
            hv1.w = pk2(ms[14] * inv, ms[15] * inv);
            *(uint4*)&Ahi[r * ALD + sub * 16]     = hv0;
            *(uint4*)&Ahi[r * ALD + sub * 16 + 8] = hv1;
        }
        __syncthreads();
        #pragma unroll
        for (int ks = 0; ks < 4; ++ks) {
            bf16x8 wh = *(const bf16x8*)&Wt_l[(size_t)(8 * m + ks) * 4096 + w * 512 + l * 8];
            bf16x8 wl = *(const bf16x8*)&Wt_l[(size_t)(8 * m + 4 + ks) * 4096 + w * 512 + l * 8];
            int k0 = ks * 32 + koff;
            #pragma unroll
            for (int rt = 0; rt < 4; ++rt) {
                bf16x8 ah = *(const bf16x8*)&Ahi[(rt * 16 + l15) * ALD + k0];
                acc[rt] = __builtin_amdgcn_mfma_f32_16x16x32_bf16(ah, wh, acc[rt], 0, 0, 0);
                acc[rt] = __builtin_amdgcn_mfma_f32_16x16x32_bf16(ah, wl, acc[rt], 0, 0, 0);
            }
        }
        __syncthreads();
    }

    // ---- dump acc+bias to f32 LDS
    {
        int col = w * 16 + l15;
        float bv = blsum_l[col];
        int rloc = (l >> 4) * 4;
        #pragma unroll
        for (int rt = 0; rt < 4; ++rt) {
            #pragma unroll
            for (int i = 0; i < 4; ++i) {
                Ln[(rloc + rt * 16 + i) * LNLD + col] = acc[rt][i] + bv;
            }
        }
    }
    __syncthreads();
    // ---- fused LayerNorm
    {
        float* Lr = Ln + r * LNLD + sub * 16;
        float4 v0 = *(const float4*)(Lr + 0);
        float4 v1 = *(const float4*)(Lr + 4);
        float4 v2 = *(const float4*)(Lr + 8);
        float4 v3 = *(const float4*)(Lr + 12);
        float s = v0.x + v0.y + v0.z + v0.w + v1.x + v1.y + v1.z + v1.w
                + v2.x + v2.y + v2.z + v2.w + v3.x + v3.y + v3.z + v3.w;
        float q = v0.x*v0.x + v0.y*v0.y + v0.z*v0.z + v0.w*v0.w
                + v1.x*v1.x + v1.y*v1.y + v1.z*v1.z + v1.w*v1.w
                + v2.x*v2.x + v2.y*v2.y + v2.z*v2.z + v2.w*v2.w
                + v3.x*v3.x + v3.y*v3.y + v3.z*v3.z + v3.w*v3.w;
        #pragma unroll
        for (int o = 1; o < 8; o <<= 1) { s += __shfl_xor(s, o); q += __shfl_xor(q, o); }
        float mu = s * (1.0f / HH);
        float var = q * (1.0f / HH) - mu * mu;
        float rs = rsqrtf(var + 1e-5f);
        const float4* g4 = (const float4*)(gamma + sub * 16);
        const float4* b4 = (const float4*)(beta + sub * 16);
        float4 g0 = g4[0], g1 = g4[1], g2 = g4[2], g3 = g4[3];
        float4 e0 = b4[0], e1 = b4[1], e2 = b4[2], e3 = b4[3];
        float ov[16];
        ov[0]  = (v0.x - mu) * rs * g0.x + e0.x; ov[1]  = (v0.y - mu) * rs * g0.y + e0.y;
        ov[2]  = (v0.z - mu) * rs * g0.z + e0.z; ov[3]  = (v0.w - mu) * rs * g0.w + e0.w;
        ov[4]  = (v1.x - mu) * rs * g1.x + e1.x; ov[5]  = (v1.y - mu) * rs * g1.y + e1.y;
        ov[6]  = (v1.z - mu) * rs * g1.z + e1.z; ov[7]  = (v1.w - mu) * rs * g1.w + e1.w;
        ov[8]  = (v2.x - mu) * rs * g2.x + e2.x; ov[9]  = (v2.y - mu) * rs * g2.y + e2.y;
        ov[10] = (v2.z - mu) * rs * g2.z + e2.z; ov[11] = (v2.w - mu) * rs * g2.w + e2.w;
        ov[12] = (v3.x - mu) * rs * g3.x + e3.x; ov[13] = (v3.y - mu) * rs * g3.y + e3.y;
        ov[14] = (v3.z - mu) * rs * g3.z + e3.z; ov[15] = (v3.w - mu) * rs * g3.w + e3.w;
        if (gr < NN) {
            uint4 o0, o1;
            o0.x = pk2(ov[0], ov[1]);  o0.y = pk2(ov[2], ov[3]);
            o0.z = pk2(ov[4], ov[5]);  o0.w = pk2(ov[6], ov[7]);
            o1.x = pk2(ov[8], ov[9]);  o1.y = pk2(ov[10], ov[11]);
            o1.z = pk2(ov[12], ov[13]); o1.w = pk2(ov[14], ov[15]);
            uint4* op = (uint4*)&hout16[(size_t)gr * 128 + sub * 16];
            op[0] = o0; op[1] = o1;
        }
        if (DOPOOL) {
            // write LN'd f32 back to own slice (exclusive ownership, no race)
            #pragma unroll
            for (int j = 0; j < 16; ++j) Lr[j] = ov[j];
        }
    }
    if (DOPOOL) {
        __syncthreads();
        int g0 = gidx[0];
        int g1 = gidx[nrow - 1];
        int d = tid & 127, q = tid >> 7;
        for (int g = g0; g <= g1; ++g) {
            float s = 0.f, m = -INFINITY;
            for (int rr = q; rr < 64; rr += 4) {
                if (gidx[rr] == g) {
                    float v = Ln[rr * LNLD + d];
                    s += v; m = fmaxf(m, v);
                }
            }
            qsum[q][d] = s; qmax[q][d] = m;
            __syncthreads();
            if (tid < HH) {
                float ss = qsum[0][tid] + qsum[1][tid] + qsum[2][tid] + qsum[3][tid];
                float mm = fmaxf(fmaxf(qmax[0][tid], qmax[1][tid]),
                                 fmaxf(qmax[2][tid], qmax[3][tid]));
                atomicAdd(&psum[g * HH + tid], ss);
                atomicMax(&pmaxu[g * HH + tid], fenc(mm));
            }
            __syncthreads();
        }
    }
}

// ================================================================ pool finalize (64 x 128)
__global__ void poolout_kernel(const float* __restrict__ psum, const unsigned* __restrict__ pmaxu,
                               const int* __restrict__ batch, float* __restrict__ out) {
    int g = blockIdx.x;
    int d = threadIdx.x;
    int start, end;
    {
        int lo = 0, hi = NN;
        while (lo < hi) { int mid = (lo + hi) >> 1; if (batch[mid] < g) lo = mid + 1; else hi = mid; }
        start = lo;
        hi = NN;
        while (lo < hi) { int mid = (lo + hi) >> 1; if (batch[mid] < g + 1) lo = mid + 1; else hi = mid; }
        end = lo;
    }
    int cg = end - start;
    float s = psum[g * HH + d];
    float m = fdec(pmaxu[g * HH + d]);
    out[g * 2 * HH + d] = s / fmaxf((float)cg, 1.0f);
    out[g * 2 * HH + HH + d] = (cg > 0) ? m : 0.0f;
}

// ================================================================ launch
extern "C" void kernel_launch(void* const* d_in, const int* in_sizes, int n_in,
                              void* d_out, int out_size, void* d_ws, size_t ws_size,
                              hipStream_t stream) {
    const float* x     = (const float*)d_in[0];
    const int*   ast   = (const int*)d_in[1];
    const int*   batch = (const int*)d_in[2];
    const int*   ei    = (const int*)d_in[3];
    const float* emb   = (const float*)d_in[4];
    const float* W_in  = (const float*)d_in[5];
    const float* b_in  = (const float*)d_in[6];
    const float* W_l   = (const float*)d_in[7];
    const float* b_l   = (const float*)d_in[8];
    const float* W_r   = (const float*)d_in[9];
    const float* gamma = (const float*)d_in[10];
    const float* beta  = (const float*)d_in[11];
    float* out = (float*)d_out;

    const int M  = TT * NN;
    const int NB = (M + 1023) / 1024;

    char* p = (char*)d_ws;
    unsigned short* h16a = (unsigned short*)p;  p += (size_t)NN * HH * 2;   // 25.6 MB
    unsigned short* h16b = (unsigned short*)p;  p += (size_t)NN * HH * 2;   // 25.6 MB
    unsigned short* Wt16 = (unsigned short*)p;  p += (size_t)LL * WLSZ * 2;
    unsigned short* Wp_in = (unsigned short*)p; p += (size_t)32768 * 2;     // 64 KB
    float* blsum = (float*)p;                   p += LL * HH * 4;
    float* psum = (float*)p;                    p += (size_t)BB * HH * 4;
    unsigned* pmaxu = (unsigned*)p;             p += (size_t)BB * HH * 4;
    int* cnt    = (int*)p;                      p += (size_t)M * 4;
    int* offs   = (int*)p;                      p += (size_t)M * 4;
    int* cursor = (int*)p;                      p += (size_t)M * 4;
    int* csr    = (int*)p;                      p += (size_t)TT * EE * 4;
    int* bsums  = (int*)p;

    int conv_grid = (NN + 63) / 64;

    hipMemsetAsync(cnt, 0, (size_t)M * sizeof(int), stream);
    wprep_kernel<<<(LL * 4 * HH * HH + 255) / 256, 256, 0, stream>>>(
        W_l, W_r, b_l, W_in, Wt16, Wp_in, blsum, psum, pmaxu);
    input_proj_kernel<<<conv_grid, 512, 0, stream>>>(x, ast, emb, Wp_in, b_in, h16a, ei, cnt);
    scan1_kernel<<<NB, 256, 0, stream>>>(cnt, offs, bsums, M);
    scan2_kernel<<<1, 512, 0, stream>>>(bsums, NB);
    scan3_kernel<<<(M + 255) / 256, 256, 0, stream>>>(offs, bsums, cursor, M);
    fill_kernel<<<(TT * EE + 255) / 256, 256, 0, stream>>>(ei, cursor, csr);
    // layer 0
    conv_kernel<0><<<conv_grid, 512, 0, stream>>>(h16a, Wt16, blsum, gamma, beta,
                                                  offs, cnt, csr, h16b,
                                                  batch, nullptr, nullptr);
    // layer 1 + fused pool partials
    conv_kernel<1><<<conv_grid, 512, 0, stream>>>(h16b, Wt16 + (size_t)WLSZ, blsum + HH,
                                                  gamma + HH, beta + HH,
                                                  offs, cnt, csr, h16a,
                                                  batch, psum, pmaxu);
    poolout_kernel<<<BB, HH, 0, stream>>>(psum, pmaxu, batch, out);
}

// Round 16
// 298.715 us; speedup vs baseline: 3.1200x; 1.0327x over previous
//
#include <hip/hip_runtime.h>
#include <hip/hip_bf16.h>
#include <math.h>

#define NN 100000   // nodes
#define EE 300000   // edges per type
#define TT 3        // edge types
#define LL 2        // layers
#define HH 128      // hidden
#define FF 5        // node feat
#define TE 64       // type embed
#define NT 200      // num ast types
#define BB 64       // graphs
#define CSRCAP 512  // per-type per-block LDS index cap (mean ~192)
#define WLSZ 131072 // per-layer fragment-packed weight size (shorts)
#define KIN 96      // padded K for input projection (69 -> 96)
#define IALD 104    // input-proj LDS row stride (shorts)

typedef short bf16x8 __attribute__((ext_vector_type(8)));
typedef float f32x4  __attribute__((ext_vector_type(4)));

__device__ __forceinline__ float bf2f(unsigned short u) {
    union { unsigned i; float f; } v; v.i = ((unsigned)u) << 16; return v.f;
}
__device__ __forceinline__ float bflo(unsigned u) {
    union { unsigned i; float f; } v; v.i = u << 16; return v.f;
}
__device__ __forceinline__ float bfhi(unsigned u) {
    union { unsigned i; float f; } v; v.i = u & 0xFFFF0000u; return v.f;
}
__device__ __forceinline__ unsigned short f2bf(float f) {
    union { float f; unsigned i; } v; v.f = f;
    unsigned b = v.i + (0x7FFFu + ((v.i >> 16) & 1u));   // RNE
    return (unsigned short)(b >> 16);
}
__device__ __forceinline__ unsigned pk2(float a, float b) {
    return (unsigned)f2bf(a) | ((unsigned)f2bf(b) << 16);
}
__device__ __forceinline__ void split_bf(float x, unsigned short& hi, unsigned short& lo) {
    hi = f2bf(x);
    lo = f2bf(x - bf2f(hi));
}
// monotone f32 <-> u32 encoding for atomicMax
__device__ __forceinline__ unsigned fenc(float f) {
    union { float f; unsigned u; } v; v.f = f;
    return (v.u & 0x80000000u) ? ~v.u : (v.u | 0x80000000u);
}
__device__ __forceinline__ float fdec(unsigned key) {
    union { float f; unsigned u; } v;
    v.u = (key & 0x80000000u) ? (key ^ 0x80000000u) : ~key;
    return v.f;
}
#define PMAX_INIT 0x007FFFFFu   // fenc(-inf)

// ================================================================ scan kernels (validated R2/R13)
__global__ __launch_bounds__(256) void scan1_kernel(const int* __restrict__ cnt,
                                                    int* __restrict__ offs,
                                                    int* __restrict__ bsums, int M) {
    int tid = threadIdx.x;
    int base = blockIdx.x * 1024 + tid * 4;
    int a0 = 0, a1 = 0, a2 = 0, a3 = 0;
    if (base + 3 < M) { int4 v = *(const int4*)&cnt[base]; a0 = v.x; a1 = v.y; a2 = v.z; a3 = v.w; }
    else {
        if (base + 0 < M) a0 = cnt[base + 0];
        if (base + 1 < M) a1 = cnt[base + 1];
        if (base + 2 < M) a2 = cnt[base + 2];
        if (base + 3 < M) a3 = cnt[base + 3];
    }
    int s = a0 + a1 + a2 + a3;
    int lane = tid & 63, wv = tid >> 6;
    int x = s;
    #pragma unroll
    for (int o = 1; o < 64; o <<= 1) { int y = __shfl_up(x, o); if (lane >= o) x += y; }
    __shared__ int wsum[4];
    if (lane == 63) wsum[wv] = x;
    __syncthreads();
    int add = 0;
    for (int w = 0; w < wv; ++w) add += wsum[w];
    int incl = x + add;
    int e0 = incl - s, e1 = e0 + a0, e2 = e1 + a1, e3 = e2 + a2;
    if (base + 0 < M) offs[base + 0] = e0;
    if (base + 1 < M) offs[base + 1] = e1;
    if (base + 2 < M) offs[base + 2] = e2;
    if (base + 3 < M) offs[base + 3] = e3;
    if (tid == 255) bsums[blockIdx.x] = incl;
}

__global__ __launch_bounds__(512) void scan2_kernel(int* __restrict__ bsums, int NB) {
    int tid = threadIdx.x;
    int s = (tid < NB) ? bsums[tid] : 0;
    int lane = tid & 63, wv = tid >> 6;
    int x = s;
    #pragma unroll
    for (int o = 1; o < 64; o <<= 1) { int y = __shfl_up(x, o); if (lane >= o) x += y; }
    __shared__ int wsum[8];
    if (lane == 63) wsum[wv] = x;
    __syncthreads();
    int add = 0;
    for (int w = 0; w < wv; ++w) add += wsum[w];
    if (tid < NB) bsums[tid] = x + add - s;
}

__global__ void scan3_kernel(int* __restrict__ offs, const int* __restrict__ bsums,
                             int* __restrict__ cursor, int M) {
    int i = blockIdx.x * 256 + threadIdx.x;
    if (i >= M) return;
    int v = offs[i] + bsums[i >> 10];
    offs[i] = v;
    cursor[i] = v;
}

__global__ void fill_kernel(const int* __restrict__ ei, int* __restrict__ cursor,
                            int* __restrict__ csr) {
    int i = blockIdx.x * blockDim.x + threadIdx.x;
    if (i >= TT * EE) return;
    int t = i / EE, e = i - t * EE;
    int src = ei[(t * 2 + 0) * EE + e];
    int dst = ei[(t * 2 + 1) * EE + e];
    int pos = atomicAdd(&cursor[t * NN + dst], 1);
    csr[pos] = src;
}

// ================================================================ weight prep (+ psum/pmax init, validated R15)
__global__ void wprep_kernel(const float* __restrict__ W_l, const float* __restrict__ W_r,
                             const float* __restrict__ b_l, const float* __restrict__ W_in,
                             unsigned short* __restrict__ Wt16, unsigned short* __restrict__ Wp,
                             float* __restrict__ blsum,
                             float* __restrict__ psum, unsigned* __restrict__ pmaxu) {
    int i = blockIdx.x * 256 + threadIdx.x;
    if (i < LL * 4 * HH * HH) {
        int lm = i >> 14;
        int ck = i & 16383;
        int col = ck >> 7, k = ck & 127;
        int l = lm >> 2, m = lm & 3;
        float v;
        if (m == 0) {
            v = 0.f;
            for (int t = 0; t < TT; ++t)
                v += W_r[(((size_t)(l * TT + t)) << 14) + k * HH + col];
        } else {
            v = W_l[(((size_t)(l * TT + (m - 1))) << 14) + k * HH + col];
        }
        unsigned short hi, lo;
        split_bf(v, hi, lo);
        int cg = col >> 4, l15 = col & 15;
        int ks = k >> 5, lh = (k >> 3) & 3, j = k & 7;
        int lane = lh * 16 + l15;
        size_t base = (size_t)l * WLSZ;
        int Phi = (m * 2 + 0) * 4 + ks;
        int Plo = Phi + 4;
        Wt16[base + (size_t)Phi * 4096 + cg * 512 + lane * 8 + j] = hi;
        Wt16[base + (size_t)Plo * 4096 + cg * 512 + lane * 8 + j] = lo;
    }
    if (i < KIN * HH) {
        int col = i & 127, k = i >> 7;
        float v = (k < TE + FF) ? W_in[k * HH + col] : 0.f;
        unsigned short hi, lo;
        split_bf(v, hi, lo);
        int cg = col >> 4, l15 = col & 15;
        int ks = k >> 5, lh = (k >> 3) & 3, j = k & 7;
        int lane = lh * 16 + l15;
        Wp[(size_t)ks * 4096 + cg * 512 + lane * 8 + j]       = hi;
        Wp[(size_t)(4 + ks) * 4096 + cg * 512 + lane * 8 + j] = lo;
    }
    if (i < LL * HH) {
        int l = i >> 7, j = i & 127;
        float s = 0.f;
        for (int t = 0; t < TT; ++t) s += b_l[(l * TT + t) * HH + j];
        blsum[i] = s;
    }
    if (i < BB * HH) {
        psum[i] = 0.f;
        pmaxu[i] = PMAX_INIT;
    }
}

// ================================================================ input projection + fused edge count (validated R15)
__global__ __launch_bounds__(512) void input_proj_kernel(
    const float* __restrict__ x, const int* __restrict__ ast,
    const float* __restrict__ emb, const unsigned short* __restrict__ Wp,
    const float* __restrict__ b_in, unsigned short* __restrict__ h16,
    const int* __restrict__ ei, int* __restrict__ cnt)
{
    __shared__ unsigned short Ahi[64 * IALD];   // 13.3 KB
    __shared__ unsigned short Alo[64 * IALD];   // 13.3 KB

    int tid = threadIdx.x;
    int row0 = blockIdx.x * 64;
    int w = tid >> 6, l = tid & 63;
    int l15 = l & 15, koff = (l >> 4) * 8;

    // ---- fused count (grid-stride over all edges)
    {
        int gsz = gridDim.x * 512;
        for (int i = blockIdx.x * 512 + tid; i < TT * EE; i += gsz) {
            int t = i / EE, e = i - t * EE;
            atomicAdd(&cnt[t * NN + ei[(t * 2 + 1) * EE + e]], 1);
        }
    }

    // ---- stage A-tile: 8 threads x 12 cols per row (96 cols)
    {
        int r = tid >> 3, sub = tid & 7;
        int gr = row0 + r;
        float v[12];
        #pragma unroll
        for (int j = 0; j < 12; ++j) v[j] = 0.f;
        if (gr < NN) {
            int a = ast[gr];
            #pragma unroll
            for (int j = 0; j < 12; ++j) {
                int k = sub * 12 + j;
                if (k < TE) v[j] = emb[a * TE + k];
                else if (k < TE + FF) v[j] = x[gr * FF + (k - TE)];
            }
        }
        unsigned short hs[12], ls[12];
        #pragma unroll
        for (int j = 0; j < 12; ++j) split_bf(v[j], hs[j], ls[j]);
        unsigned uh[6], ul[6];
        #pragma unroll
        for (int q = 0; q < 6; ++q) {
            uh[q] = (unsigned)hs[2 * q] | ((unsigned)hs[2 * q + 1] << 16);
            ul[q] = (unsigned)ls[2 * q] | ((unsigned)ls[2 * q + 1] << 16);
        }
        int base = r * IALD + sub * 12;
        uint2 h0; h0.x = uh[0]; h0.y = uh[1];
        uint2 h1; h1.x = uh[2]; h1.y = uh[3];
        uint2 h2; h2.x = uh[4]; h2.y = uh[5];
        uint2 l0; l0.x = ul[0]; l0.y = ul[1];
        uint2 l1; l1.x = ul[2]; l1.y = ul[3];
        uint2 l2; l2.x = ul[4]; l2.y = ul[5];
        *(uint2*)&Ahi[base + 0] = h0;
        *(uint2*)&Ahi[base + 4] = h1;
        *(uint2*)&Ahi[base + 8] = h2;
        *(uint2*)&Alo[base + 0] = l0;
        *(uint2*)&Alo[base + 4] = l1;
        *(uint2*)&Alo[base + 8] = l2;
    }
    __syncthreads();

    // ---- MFMA: 3 k-steps
    f32x4 acc[4] = {};
    #pragma unroll
    for (int ks = 0; ks < 3; ++ks) {
        bf16x8 wh = *(const bf16x8*)&Wp[(size_t)ks * 4096 + w * 512 + l * 8];
        bf16x8 wl = *(const bf16x8*)&Wp[(size_t)(4 + ks) * 4096 + w * 512 + l * 8];
        int k0 = ks * 32 + koff;
        #pragma unroll
        for (int rt = 0; rt < 4; ++rt) {
            bf16x8 ah = *(const bf16x8*)&Ahi[(rt * 16 + l15) * IALD + k0];
            bf16x8 al = *(const bf16x8*)&Alo[(rt * 16 + l15) * IALD + k0];
            acc[rt] = __builtin_amdgcn_mfma_f32_16x16x32_bf16(ah, wh, acc[rt], 0, 0, 0);
            acc[rt] = __builtin_amdgcn_mfma_f32_16x16x32_bf16(al, wh, acc[rt], 0, 0, 0);
            acc[rt] = __builtin_amdgcn_mfma_f32_16x16x32_bf16(ah, wl, acc[rt], 0, 0, 0);
        }
    }

    // ---- bias + bf16 store (m89 C/D layout)
    {
        int col = w * 16 + l15;
        float bv = b_in[col];
        int rbase = row0 + (l >> 4) * 4;
        #pragma unroll
        for (int rt = 0; rt < 4; ++rt) {
            #pragma unroll
            for (int i = 0; i < 4; ++i) {
                int grr = rbase + rt * 16 + i;
                if (grr < NN) h16[(size_t)grr * HH + col] = f2bf(acc[rt][i] + bv);
            }
        }
    }
}

// ================================================================ conv layer + fused LN (+ pool partials via direct atomics)
// R16: qsum/qmax LDS scratch removed (was tipping LDS past the 4-block/CU
// granule boundary -> 3 blocks, conv 82->107us). Pool partials now issue one
// atomic per (graph, col, quarter) directly. LDS back to ~34.3 KB.
#define ALD 136
#define LNLD 132

template<int DOPOOL>
__global__ __launch_bounds__(512) void conv_kernel(
    const unsigned short* __restrict__ h16,
    const unsigned short* __restrict__ Wt_l,
    const float* __restrict__ blsum_l,
    const float* __restrict__ gamma, const float* __restrict__ beta,
    const int* __restrict__ offs, const int* __restrict__ cnt, const int* __restrict__ csr,
    unsigned short* __restrict__ hout16,
    const int* __restrict__ batch, float* __restrict__ psum, unsigned* __restrict__ pmaxu)
{
    __shared__ char smem[64 * LNLD * 4];         // 33.8 KB (Ln overlays Ahi+csr)
    unsigned short* Ahi = (unsigned short*)smem;             // 17.4 KB
    int* csr_lds = (int*)(smem + 64 * ALD * 2);              // 6 KB  [TT][CSRCAP]
    float* Ln = (float*)smem;                                // 33.8 KB (reused at end)
    __shared__ int base_lds[TT], len_lds[TT], flag_lds[TT];
    __shared__ int gidx[64];                                  // 256 B

    int tid = threadIdx.x;
    int row0 = blockIdx.x * 64;
    int nrow = min(64, NN - row0);
    int w = tid >> 6, l = tid & 63;
    int l15 = l & 15, koff = (l >> 4) * 8;

    if (tid < TT) {
        int t = tid;
        int last = row0 + nrow - 1;
        int b = offs[t * NN + row0];
        int e = offs[t * NN + last] + cnt[t * NN + last];
        base_lds[t] = b;
        len_lds[t] = e - b;
        flag_lds[t] = (e - b) <= CSRCAP;
    }
    if (DOPOOL && tid < 64) gidx[tid] = (row0 + tid < NN) ? batch[row0 + tid] : -1;
    __syncthreads();
    #pragma unroll
    for (int t = 0; t < TT; ++t) {
        if (flag_lds[t]) {
            int b = base_lds[t], len = len_lds[t];
            for (int i = tid; i < len; i += 512) csr_lds[t * CSRCAP + i] = csr[b + i];
        }
    }
    __syncthreads();

    int r = tid >> 3, sub = tid & 7;
    int gr = row0 + r;

    f32x4 acc[4] = {};

    #pragma unroll
    for (int m = 0; m < 4; ++m) {
        if (m == 0) {
            #pragma unroll
            for (int s2 = 0; s2 < 2; ++s2) {
                int c16 = s2 * 512 + tid;
                int rr = c16 >> 4, k0 = (c16 & 15) * 8;
                int grr = row0 + rr;
                uint4 hv = {0u, 0u, 0u, 0u};
                if (grr < NN) hv = *(const uint4*)&h16[(size_t)grr * 128 + k0];
                *(uint4*)&Ahi[rr * ALD + k0] = hv;
            }
        } else {
            int t = m - 1;
            float ms[16];
            #pragma unroll
            for (int j = 0; j < 16; ++j) ms[j] = 0.f;
            float inv = 0.f;
            if (gr < NN) {
                int o = offs[t * NN + gr];
                int c = cnt[t * NN + gr];
                inv = (c > 0) ? 1.0f / (float)c : 0.0f;
                bool inl = flag_lds[t] != 0;
                int rel = o - base_lds[t];
                const unsigned* h16u = (const unsigned*)h16;
                for (int j = 0; j < c; ++j) {
                    int src = inl ? csr_lds[t * CSRCAP + rel + j] : csr[o + j];
                    const uint4* hp = (const uint4*)&h16u[(size_t)src * 64 + sub * 8];
                    uint4 v0 = hp[0], v1 = hp[1];
                    ms[0]  += bflo(v0.x); ms[1]  += bfhi(v0.x);
                    ms[2]  += bflo(v0.y); ms[3]  += bfhi(v0.y);
                    ms[4]  += bflo(v0.z); ms[5]  += bfhi(v0.z);
                    ms[6]  += bflo(v0.w); ms[7]  += bfhi(v0.w);
                    ms[8]  += bflo(v1.x); ms[9]  += bfhi(v1.x);
                    ms[10] += bflo(v1.y); ms[11] += bfhi(v1.y);
                    ms[12] += bflo(v1.z); ms[13] += bfhi(v1.z);
                    ms[14] += bflo(v1.w); ms[15] += bfhi(v1.w);
                }
            }
            uint4 hv0, hv1;
            hv0.x = pk2(ms[0] * inv,  ms[1] * inv);
            hv0.y = pk2(ms[2] * inv,  ms[3] * inv);
            hv0.z = pk2(ms[4] * inv,  ms[5] * inv);
            hv0.w = pk2(ms[6] * inv,  ms[7] * inv);
            hv1.x = pk2(ms[8] * inv,  ms[9] * inv);
            hv1.y = pk2(ms[10] * inv, ms[11] * inv);
            hv1.z = pk2(ms[12] * inv, ms[13] * inv);
            hv1.w = pk2(ms[14] * inv, ms[15] * inv);
            *(uint4*)&Ahi[r * ALD + sub * 16]     = hv0;
            *(uint4*)&Ahi[r * ALD + sub * 16 + 8] = hv1;
        }
        __syncthreads();
        #pragma unroll
        for (int ks = 0; ks < 4; ++ks) {
            bf16x8 wh = *(const bf16x8*)&Wt_l[(size_t)(8 * m + ks) * 4096 + w * 512 + l * 8];
            bf16x8 wl = *(const bf16x8*)&Wt_l[(size_t)(8 * m + 4 + ks) * 4096 + w * 512 + l * 8];
            int k0 = ks * 32 + koff;
            #pragma unroll
            for (int rt = 0; rt < 4; ++rt) {
                bf16x8 ah = *(const bf16x8*)&Ahi[(rt * 16 + l15) * ALD + k0];
                acc[rt] = __builtin_amdgcn_mfma_f32_16x16x32_bf16(ah, wh, acc[rt], 0, 0, 0);
                acc[rt] = __builtin_amdgcn_mfma_f32_16x16x32_bf16(ah, wl, acc[rt], 0, 0, 0);
            }
        }
        __syncthreads();
    }

    // ---- dump acc+bias to f32 LDS
    {
        int col = w * 16 + l15;
        float bv = blsum_l[col];
        int rloc = (l >> 4) * 4;
        #pragma unroll
        for (int rt = 0; rt < 4; ++rt) {
            #pragma unroll
            for (int i = 0; i < 4; ++i) {
                Ln[(rloc + rt * 16 + i) * LNLD + col] = acc[rt][i] + bv;
            }
        }
    }
    __syncthreads();
    // ---- fused LayerNorm
    {
        float* Lr = Ln + r * LNLD + sub * 16;
        float4 v0 = *(const float4*)(Lr + 0);
        float4 v1 = *(const float4*)(Lr + 4);
        float4 v2 = *(const float4*)(Lr + 8);
        float4 v3 = *(const float4*)(Lr + 12);
        float s = v0.x + v0.y + v0.z + v0.w + v1.x + v1.y + v1.z + v1.w
                + v2.x + v2.y + v2.z + v2.w + v3.x + v3.y + v3.z + v3.w;
        float q = v0.x*v0.x + v0.y*v0.y + v0.z*v0.z + v0.w*v0.w
                + v1.x*v1.x + v1.y*v1.y + v1.z*v1.z + v1.w*v1.w
                + v2.x*v2.x + v2.y*v2.y + v2.z*v2.z + v2.w*v2.w
                + v3.x*v3.x + v3.y*v3.y + v3.z*v3.z + v3.w*v3.w;
        #pragma unroll
        for (int o = 1; o < 8; o <<= 1) { s += __shfl_xor(s, o); q += __shfl_xor(q, o); }
        float mu = s * (1.0f / HH);
        float var = q * (1.0f / HH) - mu * mu;
        float rs = rsqrtf(var + 1e-5f);
        const float4* g4 = (const float4*)(gamma + sub * 16);
        const float4* b4 = (const float4*)(beta + sub * 16);
        float4 g0 = g4[0], g1 = g4[1], g2 = g4[2], g3 = g4[3];
        float4 e0 = b4[0], e1 = b4[1], e2 = b4[2], e3 = b4[3];
        float ov[16];
        ov[0]  = (v0.x - mu) * rs * g0.x + e0.x; ov[1]  = (v0.y - mu) * rs * g0.y + e0.y;
        ov[2]  = (v0.z - mu) * rs * g0.z + e0.z; ov[3]  = (v0.w - mu) * rs * g0.w + e0.w;
        ov[4]  = (v1.x - mu) * rs * g1.x + e1.x; ov[5]  = (v1.y - mu) * rs * g1.y + e1.y;
        ov[6]  = (v1.z - mu) * rs * g1.z + e1.z; ov[7]  = (v1.w - mu) * rs * g1.w + e1.w;
        ov[8]  = (v2.x - mu) * rs * g2.x + e2.x; ov[9]  = (v2.y - mu) * rs * g2.y + e2.y;
        ov[10] = (v2.z - mu) * rs * g2.z + e2.z; ov[11] = (v2.w - mu) * rs * g2.w + e2.w;
        ov[12] = (v3.x - mu) * rs * g3.x + e3.x; ov[13] = (v3.y - mu) * rs * g3.y + e3.y;
        ov[14] = (v3.z - mu) * rs * g3.z + e3.z; ov[15] = (v3.w - mu) * rs * g3.w + e3.w;
        if (gr < NN) {
            uint4 o0, o1;
            o0.x = pk2(ov[0], ov[1]);  o0.y = pk2(ov[2], ov[3]);
            o0.z = pk2(ov[4], ov[5]);  o0.w = pk2(ov[6], ov[7]);
            o1.x = pk2(ov[8], ov[9]);  o1.y = pk2(ov[10], ov[11]);
            o1.z = pk2(ov[12], ov[13]); o1.w = pk2(ov[14], ov[15]);
            uint4* op = (uint4*)&hout16[(size_t)gr * 128 + sub * 16];
            op[0] = o0; op[1] = o1;
        }
        if (DOPOOL) {
            // write LN'd f32 back to own slice (exclusive ownership, no race)
            #pragma unroll
            for (int j = 0; j < 16; ++j) Lr[j] = ov[j];
        }
    }
    if (DOPOOL) {
        __syncthreads();
        // per-quarter partials -> direct atomics (no LDS scratch)
        int g0 = gidx[0];
        int g1 = gidx[nrow - 1];
        int d = tid & 127, q = tid >> 7;
        for (int g = g0; g <= g1; ++g) {
            float s = 0.f, m = -INFINITY;
            bool any = false;
            for (int rr = q; rr < 64; rr += 4) {
                if (gidx[rr] == g) {
                    float v = Ln[rr * LNLD + d];
                    s += v; m = fmaxf(m, v);
                    any = true;
                }
            }
            if (any) {
                atomicAdd(&psum[g * HH + d], s);
                atomicMax(&pmaxu[g * HH + d], fenc(m));
            }
        }
    }
}

// ================================================================ pool finalize (64 x 128)
__global__ void poolout_kernel(const float* __restrict__ psum, const unsigned* __restrict__ pmaxu,
                               const int* __restrict__ batch, float* __restrict__ out) {
    int g = blockIdx.x;
    int d = threadIdx.x;
    int start, end;
    {
        int lo = 0, hi = NN;
        while (lo < hi) { int mid = (lo + hi) >> 1; if (batch[mid] < g) lo = mid + 1; else hi = mid; }
        start = lo;
        hi = NN;
        while (lo < hi) { int mid = (lo + hi) >> 1; if (batch[mid] < g + 1) lo = mid + 1; else hi = mid; }
        end = lo;
    }
    int cg = end - start;
    float s = psum[g * HH + d];
    float m = fdec(pmaxu[g * HH + d]);
    out[g * 2 * HH + d] = s / fmaxf((float)cg, 1.0f);
    out[g * 2 * HH + HH + d] = (cg > 0) ? m : 0.0f;
}

// ================================================================ launch
extern "C" void kernel_launch(void* const* d_in, const int* in_sizes, int n_in,
                              void* d_out, int out_size, void* d_ws, size_t ws_size,
                              hipStream_t stream) {
    const float* x     = (const float*)d_in[0];
    const int*   ast   = (const int*)d_in[1];
    const int*   batch = (const int*)d_in[2];
    const int*   ei    = (const int*)d_in[3];
    const float* emb   = (const float*)d_in[4];
    const float* W_in  = (const float*)d_in[5];
    const float* b_in  = (const float*)d_in[6];
    const float* W_l   = (const float*)d_in[7];
    const float* b_l   = (const float*)d_in[8];
    const float* W_r   = (const float*)d_in[9];
    const float* gamma = (const float*)d_in[10];
    const float* beta  = (const float*)d_in[11];
    float* out = (float*)d_out;

    const int M  = TT * NN;
    const int NB = (M + 1023) / 1024;

    char* p = (char*)d_ws;
    unsigned short* h16a = (unsigned short*)p;  p += (size_t)NN * HH * 2;   // 25.6 MB
    unsigned short* h16b = (unsigned short*)p;  p += (size_t)NN * HH * 2;   // 25.6 MB
    unsigned short* Wt16 = (unsigned short*)p;  p += (size_t)LL * WLSZ * 2;
    unsigned short* Wp_in = (unsigned short*)p; p += (size_t)32768 * 2;     // 64 KB
    float* blsum = (float*)p;                   p += LL * HH * 4;
    float* psum = (float*)p;                    p += (size_t)BB * HH * 4;
    unsigned* pmaxu = (unsigned*)p;             p += (size_t)BB * HH * 4;
    int* cnt    = (int*)p;                      p += (size_t)M * 4;
    int* offs   = (int*)p;                      p += (size_t)M * 4;
    int* cursor = (int*)p;                      p += (size_t)M * 4;
    int* csr    = (int*)p;                      p += (size_t)TT * EE * 4;
    int* bsums  = (int*)p;

    int conv_grid = (NN + 63) / 64;

    hipMemsetAsync(cnt, 0, (size_t)M * sizeof(int), stream);
    wprep_kernel<<<(LL * 4 * HH * HH + 255) / 256, 256, 0, stream>>>(
        W_l, W_r, b_l, W_in, Wt16, Wp_in, blsum, psum, pmaxu);
    input_proj_kernel<<<conv_grid, 512, 0, stream>>>(x, ast, emb, Wp_in, b_in, h16a, ei, cnt);
    scan1_kernel<<<NB, 256, 0, stream>>>(cnt, offs, bsums, M);
    scan2_kernel<<<1, 512, 0, stream>>>(bsums, NB);
    scan3_kernel<<<(M + 255) / 256, 256, 0, stream>>>(offs, bsums, cursor, M);
    fill_kernel<<<(TT * EE + 255) / 256, 256, 0, stream>>>(ei, cursor, csr);
    // layer 0
    conv_kernel<0><<<conv_grid, 512, 0, stream>>>(h16a, Wt16, blsum, gamma, beta,
                                                  offs, cnt, csr, h16b,
                                                  batch, nullptr, nullptr);
    // layer 1 + fused pool partials
    conv_kernel<1><<<conv_grid, 512, 0, stream>>>(h16b, Wt16 + (size_t)WLSZ, blsum + HH,
                                                  gamma + HH, beta + HH,
                                                  offs, cnt, csr, h16a,
                                                  batch, psum, pmaxu);
    poolout_kernel<<<BB, HH, 0, stream>>>(psum, pmaxu, batch, out);
}

// Round 17
// 293.565 us; speedup vs baseline: 3.1747x; 1.0175x over previous
//
#include <hip/hip_runtime.h>
#include <hip/hip_bf16.h>
#include <math.h>

#define NN 100000   // nodes
#define EE 300000   // edges per type
#define TT 3        // edge types
#define LL 2        // layers
#define HH 128      // hidden
#define FF 5        // node feat
#define TE 64       // type embed
#define NT 200      // num ast types
#define BB 64       // graphs
#define CSRCAP 512  // per-type per-block LDS index cap (mean ~192)
#define WLSZ 131072 // per-layer fragment-packed weight size (shorts)
#define KIN 96      // padded K for input projection (69 -> 96)
#define IALD 104    // input-proj LDS row stride (shorts)

typedef short bf16x8 __attribute__((ext_vector_type(8)));
typedef float f32x4  __attribute__((ext_vector_type(4)));

__device__ __forceinline__ float bf2f(unsigned short u) {
    union { unsigned i; float f; } v; v.i = ((unsigned)u) << 16; return v.f;
}
__device__ __forceinline__ float bflo(unsigned u) {
    union { unsigned i; float f; } v; v.i = u << 16; return v.f;
}
__device__ __forceinline__ float bfhi(unsigned u) {
    union { unsigned i; float f; } v; v.i = u & 0xFFFF0000u; return v.f;
}
__device__ __forceinline__ unsigned short f2bf(float f) {
    union { float f; unsigned i; } v; v.f = f;
    unsigned b = v.i + (0x7FFFu + ((v.i >> 16) & 1u));   // RNE
    return (unsigned short)(b >> 16);
}
__device__ __forceinline__ unsigned pk2(float a, float b) {
    return (unsigned)f2bf(a) | ((unsigned)f2bf(b) << 16);
}
__device__ __forceinline__ void split_bf(float x, unsigned short& hi, unsigned short& lo) {
    hi = f2bf(x);
    lo = f2bf(x - bf2f(hi));
}
// monotone f32 <-> u32 encoding for atomicMax
__device__ __forceinline__ unsigned fenc(float f) {
    union { float f; unsigned u; } v; v.f = f;
    return (v.u & 0x80000000u) ? ~v.u : (v.u | 0x80000000u);
}
__device__ __forceinline__ float fdec(unsigned key) {
    union { float f; unsigned u; } v;
    v.u = (key & 0x80000000u) ? (key ^ 0x80000000u) : ~key;
    return v.f;
}
#define PMAX_INIT 0x007FFFFFu   // fenc(-inf)

// ================================================================ scan kernels (validated R2/R13)
__global__ __launch_bounds__(256) void scan1_kernel(const int* __restrict__ cnt,
                                                    int* __restrict__ offs,
                                                    int* __restrict__ bsums, int M) {
    int tid = threadIdx.x;
    int base = blockIdx.x * 1024 + tid * 4;
    int a0 = 0, a1 = 0, a2 = 0, a3 = 0;
    if (base + 3 < M) { int4 v = *(const int4*)&cnt[base]; a0 = v.x; a1 = v.y; a2 = v.z; a3 = v.w; }
    else {
        if (base + 0 < M) a0 = cnt[base + 0];
        if (base + 1 < M) a1 = cnt[base + 1];
        if (base + 2 < M) a2 = cnt[base + 2];
        if (base + 3 < M) a3 = cnt[base + 3];
    }
    int s = a0 + a1 + a2 + a3;
    int lane = tid & 63, wv = tid >> 6;
    int x = s;
    #pragma unroll
    for (int o = 1; o < 64; o <<= 1) { int y = __shfl_up(x, o); if (lane >= o) x += y; }
    __shared__ int wsum[4];
    if (lane == 63) wsum[wv] = x;
    __syncthreads();
    int add = 0;
    for (int w = 0; w < wv; ++w) add += wsum[w];
    int incl = x + add;
    int e0 = incl - s, e1 = e0 + a0, e2 = e1 + a1, e3 = e2 + a2;
    if (base + 0 < M) offs[base + 0] = e0;
    if (base + 1 < M) offs[base + 1] = e1;
    if (base + 2 < M) offs[base + 2] = e2;
    if (base + 3 < M) offs[base + 3] = e3;
    if (tid == 255) bsums[blockIdx.x] = incl;
}

__global__ __launch_bounds__(512) void scan2_kernel(int* __restrict__ bsums, int NB) {
    int tid = threadIdx.x;
    int s = (tid < NB) ? bsums[tid] : 0;
    int lane = tid & 63, wv = tid >> 6;
    int x = s;
    #pragma unroll
    for (int o = 1; o < 64; o <<= 1) { int y = __shfl_up(x, o); if (lane >= o) x += y; }
    __shared__ int wsum[8];
    if (lane == 63) wsum[wv] = x;
    __syncthreads();
    int add = 0;
    for (int w = 0; w < wv; ++w) add += wsum[w];
    if (tid < NB) bsums[tid] = x + add - s;
}

__global__ void scan3_kernel(int* __restrict__ offs, const int* __restrict__ bsums,
                             int* __restrict__ cursor, int M) {
    int i = blockIdx.x * 256 + threadIdx.x;
    if (i >= M) return;
    int v = offs[i] + bsums[i >> 10];
    offs[i] = v;
    cursor[i] = v;
}

__global__ void fill_kernel(const int* __restrict__ ei, int* __restrict__ cursor,
                            int* __restrict__ csr) {
    int i = blockIdx.x * blockDim.x + threadIdx.x;
    if (i >= TT * EE) return;
    int t = i / EE, e = i - t * EE;
    int src = ei[(t * 2 + 0) * EE + e];
    int dst = ei[(t * 2 + 1) * EE + e];
    int pos = atomicAdd(&cursor[t * NN + dst], 1);
    csr[pos] = src;
}

// ================================================================ weight prep (+ cnt zero + psum/pmax init)
__global__ void wprep_kernel(const float* __restrict__ W_l, const float* __restrict__ W_r,
                             const float* __restrict__ b_l, const float* __restrict__ W_in,
                             unsigned short* __restrict__ Wt16, unsigned short* __restrict__ Wp,
                             float* __restrict__ blsum,
                             float* __restrict__ psum, unsigned* __restrict__ pmaxu,
                             int* __restrict__ cnt) {
    int i = blockIdx.x * 256 + threadIdx.x;
    int gsz = gridDim.x * 256;
    for (int z = i; z < TT * NN; z += gsz) cnt[z] = 0;   // replaces memset dispatch
    if (i < LL * 4 * HH * HH) {
        int lm = i >> 14;
        int ck = i & 16383;
        int col = ck >> 7, k = ck & 127;
        int l = lm >> 2, m = lm & 3;
        float v;
        if (m == 0) {
            v = 0.f;
            for (int t = 0; t < TT; ++t)
                v += W_r[(((size_t)(l * TT + t)) << 14) + k * HH + col];
        } else {
            v = W_l[(((size_t)(l * TT + (m - 1))) << 14) + k * HH + col];
        }
        unsigned short hi, lo;
        split_bf(v, hi, lo);
        int cg = col >> 4, l15 = col & 15;
        int ks = k >> 5, lh = (k >> 3) & 3, j = k & 7;
        int lane = lh * 16 + l15;
        size_t base = (size_t)l * WLSZ;
        int Phi = (m * 2 + 0) * 4 + ks;
        int Plo = Phi + 4;
        Wt16[base + (size_t)Phi * 4096 + cg * 512 + lane * 8 + j] = hi;
        Wt16[base + (size_t)Plo * 4096 + cg * 512 + lane * 8 + j] = lo;
    }
    if (i < KIN * HH) {
        int col = i & 127, k = i >> 7;
        float v = (k < TE + FF) ? W_in[k * HH + col] : 0.f;
        unsigned short hi, lo;
        split_bf(v, hi, lo);
        int cg = col >> 4, l15 = col & 15;
        int ks = k >> 5, lh = (k >> 3) & 3, j = k & 7;
        int lane = lh * 16 + l15;
        Wp[(size_t)ks * 4096 + cg * 512 + lane * 8 + j]       = hi;
        Wp[(size_t)(4 + ks) * 4096 + cg * 512 + lane * 8 + j] = lo;
    }
    if (i < LL * HH) {
        int l = i >> 7, j = i & 127;
        float s = 0.f;
        for (int t = 0; t < TT; ++t) s += b_l[(l * TT + t) * HH + j];
        blsum[i] = s;
    }
    if (i < BB * HH) {
        psum[i] = 0.f;
        pmaxu[i] = PMAX_INIT;
    }
}

// ================================================================ input projection + fused edge count (validated R15)
__global__ __launch_bounds__(512) void input_proj_kernel(
    const float* __restrict__ x, const int* __restrict__ ast,
    const float* __restrict__ emb, const unsigned short* __restrict__ Wp,
    const float* __restrict__ b_in, unsigned short* __restrict__ h16,
    const int* __restrict__ ei, int* __restrict__ cnt)
{
    __shared__ unsigned short Ahi[64 * IALD];   // 13.3 KB
    __shared__ unsigned short Alo[64 * IALD];   // 13.3 KB

    int tid = threadIdx.x;
    int row0 = blockIdx.x * 64;
    int w = tid >> 6, l = tid & 63;
    int l15 = l & 15, koff = (l >> 4) * 8;

    // ---- fused count (grid-stride over all edges)
    {
        int gsz = gridDim.x * 512;
        for (int i = blockIdx.x * 512 + tid; i < TT * EE; i += gsz) {
            int t = i / EE, e = i - t * EE;
            atomicAdd(&cnt[t * NN + ei[(t * 2 + 1) * EE + e]], 1);
        }
    }

    // ---- stage A-tile: 8 threads x 12 cols per row (96 cols)
    {
        int r = tid >> 3, sub = tid & 7;
        int gr = row0 + r;
        float v[12];
        #pragma unroll
        for (int j = 0; j < 12; ++j) v[j] = 0.f;
        if (gr < NN) {
            int a = ast[gr];
            #pragma unroll
            for (int j = 0; j < 12; ++j) {
                int k = sub * 12 + j;
                if (k < TE) v[j] = emb[a * TE + k];
                else if (k < TE + FF) v[j] = x[gr * FF + (k - TE)];
            }
        }
        unsigned short hs[12], ls[12];
        #pragma unroll
        for (int j = 0; j < 12; ++j) split_bf(v[j], hs[j], ls[j]);
        unsigned uh[6], ul[6];
        #pragma unroll
        for (int q = 0; q < 6; ++q) {
            uh[q] = (unsigned)hs[2 * q] | ((unsigned)hs[2 * q + 1] << 16);
            ul[q] = (unsigned)ls[2 * q] | ((unsigned)ls[2 * q + 1] << 16);
        }
        int base = r * IALD + sub * 12;
        uint2 h0; h0.x = uh[0]; h0.y = uh[1];
        uint2 h1; h1.x = uh[2]; h1.y = uh[3];
        uint2 h2; h2.x = uh[4]; h2.y = uh[5];
        uint2 l0; l0.x = ul[0]; l0.y = ul[1];
        uint2 l1; l1.x = ul[2]; l1.y = ul[3];
        uint2 l2; l2.x = ul[4]; l2.y = ul[5];
        *(uint2*)&Ahi[base + 0] = h0;
        *(uint2*)&Ahi[base + 4] = h1;
        *(uint2*)&Ahi[base + 8] = h2;
        *(uint2*)&Alo[base + 0] = l0;
        *(uint2*)&Alo[base + 4] = l1;
        *(uint2*)&Alo[base + 8] = l2;
    }
    __syncthreads();

    // ---- MFMA: 3 k-steps
    f32x4 acc[4] = {};
    #pragma unroll
    for (int ks = 0; ks < 3; ++ks) {
        bf16x8 wh = *(const bf16x8*)&Wp[(size_t)ks * 4096 + w * 512 + l * 8];
        bf16x8 wl = *(const bf16x8*)&Wp[(size_t)(4 + ks) * 4096 + w * 512 + l * 8];
        int k0 = ks * 32 + koff;
        #pragma unroll
        for (int rt = 0; rt < 4; ++rt) {
            bf16x8 ah = *(const bf16x8*)&Ahi[(rt * 16 + l15) * IALD + k0];
            bf16x8 al = *(const bf16x8*)&Alo[(rt * 16 + l15) * IALD + k0];
            acc[rt] = __builtin_amdgcn_mfma_f32_16x16x32_bf16(ah, wh, acc[rt], 0, 0, 0);
            acc[rt] = __builtin_amdgcn_mfma_f32_16x16x32_bf16(al, wh, acc[rt], 0, 0, 0);
            acc[rt] = __builtin_amdgcn_mfma_f32_16x16x32_bf16(ah, wl, acc[rt], 0, 0, 0);
        }
    }

    // ---- bias + bf16 store (m89 C/D layout)
    {
        int col = w * 16 + l15;
        float bv = b_in[col];
        int rbase = row0 + (l >> 4) * 4;
        #pragma unroll
        for (int rt = 0; rt < 4; ++rt) {
            #pragma unroll
            for (int i = 0; i < 4; ++i) {
                int grr = rbase + rt * 16 + i;
                if (grr < NN) h16[(size_t)grr * HH + col] = f2bf(acc[rt][i] + bv);
            }
        }
    }
}

// ================================================================ conv layer 0 + fused LN (R13 conv verbatim, own codegen context)
#define ALD 136
#define LNLD 132

__global__ __launch_bounds__(512) void conv0_kernel(
    const unsigned short* __restrict__ h16,
    const unsigned short* __restrict__ Wt_l,
    const float* __restrict__ blsum_l,
    const float* __restrict__ gamma, const float* __restrict__ beta,
    const int* __restrict__ offs, const int* __restrict__ cnt, const int* __restrict__ csr,
    unsigned short* __restrict__ hout16)
{
    __shared__ char smem[64 * LNLD * 4];
    unsigned short* Ahi = (unsigned short*)smem;
    int* csr_lds = (int*)(smem + 64 * ALD * 2);
    float* Ln = (float*)smem;
    __shared__ int base_lds[TT], len_lds[TT], flag_lds[TT];

    int tid = threadIdx.x;
    int row0 = blockIdx.x * 64;
    int nrow = min(64, NN - row0);
    int w = tid >> 6, l = tid & 63;
    int l15 = l & 15, koff = (l >> 4) * 8;

    if (tid < TT) {
        int t = tid;
        int last = row0 + nrow - 1;
        int b = offs[t * NN + row0];
        int e = offs[t * NN + last] + cnt[t * NN + last];
        base_lds[t] = b;
        len_lds[t] = e - b;
        flag_lds[t] = (e - b) <= CSRCAP;
    }
    __syncthreads();
    #pragma unroll
    for (int t = 0; t < TT; ++t) {
        if (flag_lds[t]) {
            int b = base_lds[t], len = len_lds[t];
            for (int i = tid; i < len; i += 512) csr_lds[t * CSRCAP + i] = csr[b + i];
        }
    }
    __syncthreads();

    int r = tid >> 3, sub = tid & 7;
    int gr = row0 + r;

    f32x4 acc[4] = {};

    #pragma unroll
    for (int m = 0; m < 4; ++m) {
        if (m == 0) {
            #pragma unroll
            for (int s2 = 0; s2 < 2; ++s2) {
                int c16 = s2 * 512 + tid;
                int rr = c16 >> 4, k0 = (c16 & 15) * 8;
                int grr = row0 + rr;
                uint4 hv = {0u, 0u, 0u, 0u};
                if (grr < NN) hv = *(const uint4*)&h16[(size_t)grr * 128 + k0];
                *(uint4*)&Ahi[rr * ALD + k0] = hv;
            }
        } else {
            int t = m - 1;
            float ms[16];
            #pragma unroll
            for (int j = 0; j < 16; ++j) ms[j] = 0.f;
            float inv = 0.f;
            if (gr < NN) {
                int o = offs[t * NN + gr];
                int c = cnt[t * NN + gr];
                inv = (c > 0) ? 1.0f / (float)c : 0.0f;
                bool inl = flag_lds[t] != 0;
                int rel = o - base_lds[t];
                const unsigned* h16u = (const unsigned*)h16;
                for (int j = 0; j < c; ++j) {
                    int src = inl ? csr_lds[t * CSRCAP + rel + j] : csr[o + j];
                    const uint4* hp = (const uint4*)&h16u[(size_t)src * 64 + sub * 8];
                    uint4 v0 = hp[0], v1 = hp[1];
                    ms[0]  += bflo(v0.x); ms[1]  += bfhi(v0.x);
                    ms[2]  += bflo(v0.y); ms[3]  += bfhi(v0.y);
                    ms[4]  += bflo(v0.z); ms[5]  += bfhi(v0.z);
                    ms[6]  += bflo(v0.w); ms[7]  += bfhi(v0.w);
                    ms[8]  += bflo(v1.x); ms[9]  += bfhi(v1.x);
                    ms[10] += bflo(v1.y); ms[11] += bfhi(v1.y);
                    ms[12] += bflo(v1.z); ms[13] += bfhi(v1.z);
                    ms[14] += bflo(v1.w); ms[15] += bfhi(v1.w);
                }
            }
            uint4 hv0, hv1;
            hv0.x = pk2(ms[0] * inv,  ms[1] * inv);
            hv0.y = pk2(ms[2] * inv,  ms[3] * inv);
            hv0.z = pk2(ms[4] * inv,  ms[5] * inv);
            hv0.w = pk2(ms[6] * inv,  ms[7] * inv);
            hv1.x = pk2(ms[8] * inv,  ms[9] * inv);
            hv1.y = pk2(ms[10] * inv, ms[11] * inv);
            hv1.z = pk2(ms[12] * inv, ms[13] * inv);
            hv1.w = pk2(ms[14] * inv, ms[15] * inv);
            *(uint4*)&Ahi[r * ALD + sub * 16]     = hv0;
            *(uint4*)&Ahi[r * ALD + sub * 16 + 8] = hv1;
        }
        __syncthreads();
        #pragma unroll
        for (int ks = 0; ks < 4; ++ks) {
            bf16x8 wh = *(const bf16x8*)&Wt_l[(size_t)(8 * m + ks) * 4096 + w * 512 + l * 8];
            bf16x8 wl = *(const bf16x8*)&Wt_l[(size_t)(8 * m + 4 + ks) * 4096 + w * 512 + l * 8];
            int k0 = ks * 32 + koff;
            #pragma unroll
            for (int rt = 0; rt < 4; ++rt) {
                bf16x8 ah = *(const bf16x8*)&Ahi[(rt * 16 + l15) * ALD + k0];
                acc[rt] = __builtin_amdgcn_mfma_f32_16x16x32_bf16(ah, wh, acc[rt], 0, 0, 0);
                acc[rt] = __builtin_amdgcn_mfma_f32_16x16x32_bf16(ah, wl, acc[rt], 0, 0, 0);
            }
        }
        __syncthreads();
    }

    {
        int col = w * 16 + l15;
        float bv = blsum_l[col];
        int rloc = (l >> 4) * 4;
        #pragma unroll
        for (int rt = 0; rt < 4; ++rt) {
            #pragma unroll
            for (int i = 0; i < 4; ++i) {
                Ln[(rloc + rt * 16 + i) * LNLD + col] = acc[rt][i] + bv;
            }
        }
    }
    __syncthreads();
    {
        const float* Lr = Ln + r * LNLD + sub * 16;
        float4 v0 = *(const float4*)(Lr + 0);
        float4 v1 = *(const float4*)(Lr + 4);
        float4 v2 = *(const float4*)(Lr + 8);
        float4 v3 = *(const float4*)(Lr + 12);
        float s = v0.x + v0.y + v0.z + v0.w + v1.x + v1.y + v1.z + v1.w
                + v2.x + v2.y + v2.z + v2.w + v3.x + v3.y + v3.z + v3.w;
        float q = v0.x*v0.x + v0.y*v0.y + v0.z*v0.z + v0.w*v0.w
                + v1.x*v1.x + v1.y*v1.y + v1.z*v1.z + v1.w*v1.w
                + v2.x*v2.x + v2.y*v2.y + v2.z*v2.z + v2.w*v2.w
                + v3.x*v3.x + v3.y*v3.y + v3.z*v3.z + v3.w*v3.w;
        #pragma unroll
        for (int o = 1; o < 8; o <<= 1) { s += __shfl_xor(s, o); q += __shfl_xor(q, o); }
        float mu = s * (1.0f / HH);
        float var = q * (1.0f / HH) - mu * mu;
        float rs = rsqrtf(var + 1e-5f);
        if (gr < NN) {
            const float4* g4 = (const float4*)(gamma + sub * 16);
            const float4* b4 = (const float4*)(beta + sub * 16);
            float4 g0 = g4[0], g1 = g4[1], g2 = g4[2], g3 = g4[3];
            float4 e0 = b4[0], e1 = b4[1], e2 = b4[2], e3 = b4[3];
            uint4 o0, o1;
            o0.x = pk2((v0.x - mu) * rs * g0.x + e0.x, (v0.y - mu) * rs * g0.y + e0.y);
            o0.y = pk2((v0.z - mu) * rs * g0.z + e0.z, (v0.w - mu) * rs * g0.w + e0.w);
            o0.z = pk2((v1.x - mu) * rs * g1.x + e1.x, (v1.y - mu) * rs * g1.y + e1.y);
            o0.w = pk2((v1.z - mu) * rs * g1.z + e1.z, (v1.w - mu) * rs * g1.w + e1.w);
            o1.x = pk2((v2.x - mu) * rs * g2.x + e2.x, (v2.y - mu) * rs * g2.y + e2.y);
            o1.y = pk2((v2.z - mu) * rs * g2.z + e2.z, (v2.w - mu) * rs * g2.w + e2.w);
            o1.z = pk2((v3.x - mu) * rs * g3.x + e3.x, (v3.y - mu) * rs * g3.y + e3.y);
            o1.w = pk2((v3.z - mu) * rs * g3.z + e3.z, (v3.w - mu) * rs * g3.w + e3.w);
            uint4* op = (uint4*)&hout16[(size_t)gr * 128 + sub * 16];
            op[0] = o0; op[1] = o1;
        }
    }
}

// ================================================================ conv layer 1 + fused LN + pool partials (separate codegen context)
__global__ __launch_bounds__(512) void conv1_kernel(
    const unsigned short* __restrict__ h16,
    const unsigned short* __restrict__ Wt_l,
    const float* __restrict__ blsum_l,
    const float* __restrict__ gamma, const float* __restrict__ beta,
    const int* __restrict__ offs, const int* __restrict__ cnt, const int* __restrict__ csr,
    unsigned short* __restrict__ hout16,
    const int* __restrict__ batch, float* __restrict__ psum, unsigned* __restrict__ pmaxu)
{
    __shared__ char smem[64 * LNLD * 4];
    unsigned short* Ahi = (unsigned short*)smem;
    int* csr_lds = (int*)(smem + 64 * ALD * 2);
    float* Ln = (float*)smem;
    __shared__ int base_lds[TT], len_lds[TT], flag_lds[TT];
    __shared__ int gidx[64];

    int tid = threadIdx.x;
    int row0 = blockIdx.x * 64;
    int nrow = min(64, NN - row0);
    int w = tid >> 6, l = tid & 63;
    int l15 = l & 15, koff = (l >> 4) * 8;

    if (tid < TT) {
        int t = tid;
        int last = row0 + nrow - 1;
        int b = offs[t * NN + row0];
        int e = offs[t * NN + last] + cnt[t * NN + last];
        base_lds[t] = b;
        len_lds[t] = e - b;
        flag_lds[t] = (e - b) <= CSRCAP;
    }
    if (tid < 64) gidx[tid] = (row0 + tid < NN) ? batch[row0 + tid] : -1;
    __syncthreads();
    #pragma unroll
    for (int t = 0; t < TT; ++t) {
        if (flag_lds[t]) {
            int b = base_lds[t], len = len_lds[t];
            for (int i = tid; i < len; i += 512) csr_lds[t * CSRCAP + i] = csr[b + i];
        }
    }
    __syncthreads();

    int r = tid >> 3, sub = tid & 7;
    int gr = row0 + r;

    f32x4 acc[4] = {};

    #pragma unroll
    for (int m = 0; m < 4; ++m) {
        if (m == 0) {
            #pragma unroll
            for (int s2 = 0; s2 < 2; ++s2) {
                int c16 = s2 * 512 + tid;
                int rr = c16 >> 4, k0 = (c16 & 15) * 8;
                int grr = row0 + rr;
                uint4 hv = {0u, 0u, 0u, 0u};
                if (grr < NN) hv = *(const uint4*)&h16[(size_t)grr * 128 + k0];
                *(uint4*)&Ahi[rr * ALD + k0] = hv;
            }
        } else {
            int t = m - 1;
            float ms[16];
            #pragma unroll
            for (int j = 0; j < 16; ++j) ms[j] = 0.f;
            float inv = 0.f;
            if (gr < NN) {
                int o = offs[t * NN + gr];
                int c = cnt[t * NN + gr];
                inv = (c > 0) ? 1.0f / (float)c : 0.0f;
                bool inl = flag_lds[t] != 0;
                int rel = o - base_lds[t];
                const unsigned* h16u = (const unsigned*)h16;
                for (int j = 0; j < c; ++j) {
                    int src = inl ? csr_lds[t * CSRCAP + rel + j] : csr[o + j];
                    const uint4* hp = (const uint4*)&h16u[(size_t)src * 64 + sub * 8];
                    uint4 v0 = hp[0], v1 = hp[1];
                    ms[0]  += bflo(v0.x); ms[1]  += bfhi(v0.x);
                    ms[2]  += bflo(v0.y); ms[3]  += bfhi(v0.y);
                    ms[4]  += bflo(v0.z); ms[5]  += bfhi(v0.z);
                    ms[6]  += bflo(v0.w); ms[7]  += bfhi(v0.w);
                    ms[8]  += bflo(v1.x); ms[9]  += bfhi(v1.x);
                    ms[10] += bflo(v1.y); ms[11] += bfhi(v1.y);
                    ms[12] += bflo(v1.z); ms[13] += bfhi(v1.z);
                    ms[14] += bflo(v1.w); ms[15] += bfhi(v1.w);
                }
            }
            uint4 hv0, hv1;
            hv0.x = pk2(ms[0] * inv,  ms[1] * inv);
            hv0.y = pk2(ms[2] * inv,  ms[3] * inv);
            hv0.z = pk2(ms[4] * inv,  ms[5] * inv);
            hv0.w = pk2(ms[6] * inv,  ms[7] * inv);
            hv1.x = pk2(ms[8] * inv,  ms[9] * inv);
            hv1.y = pk2(ms[10] * inv, ms[11] * inv);
            hv1.z = pk2(ms[12] * inv, ms[13] * inv);
            hv1.w = pk2(ms[14] * inv, ms[15] * inv);
            *(uint4*)&Ahi[r * ALD + sub * 16]     = hv0;
            *(uint4*)&Ahi[r * ALD + sub * 16 + 8] = hv1;
        }
        __syncthreads();
        #pragma unroll
        for (int ks = 0; ks < 4; ++ks) {
            bf16x8 wh = *(const bf16x8*)&Wt_l[(size_t)(8 * m + ks) * 4096 + w * 512 + l * 8];
            bf16x8 wl = *(const bf16x8*)&Wt_l[(size_t)(8 * m + 4 + ks) * 4096 + w * 512 + l * 8];
            int k0 = ks * 32 + koff;
            #pragma unroll
            for (int rt = 0; rt < 4; ++rt) {
                bf16x8 ah = *(const bf16x8*)&Ahi[(rt * 16 + l15) * ALD + k0];
                acc[rt] = __builtin_amdgcn_mfma_f32_16x16x32_bf16(ah, wh, acc[rt], 0, 0, 0);
                acc[rt] = __builtin_amdgcn_mfma_f32_16x16x32_bf16(ah, wl, acc[rt], 0, 0, 0);
            }
        }
        __syncthreads();
    }

    {
        int col = w * 16 + l15;
        float bv = blsum_l[col];
        int rloc = (l >> 4) * 4;
        #pragma unroll
        for (int rt = 0; rt < 4; ++rt) {
            #pragma unroll
            for (int i = 0; i < 4; ++i) {
                Ln[(rloc + rt * 16 + i) * LNLD + col] = acc[rt][i] + bv;
            }
        }
    }
    __syncthreads();
    {
        float* Lr = Ln + r * LNLD + sub * 16;
        float4 v0 = *(const float4*)(Lr + 0);
        float4 v1 = *(const float4*)(Lr + 4);
        float4 v2 = *(const float4*)(Lr + 8);
        float4 v3 = *(const float4*)(Lr + 12);
        float s = v0.x + v0.y + v0.z + v0.w + v1.x + v1.y + v1.z + v1.w
                + v2.x + v2.y + v2.z + v2.w + v3.x + v3.y + v3.z + v3.w;
        float q = v0.x*v0.x + v0.y*v0.y + v0.z*v0.z + v0.w*v0.w
                + v1.x*v1.x + v1.y*v1.y + v1.z*v1.z + v1.w*v1.w
                + v2.x*v2.x + v2.y*v2.y + v2.z*v2.z + v2.w*v2.w
                + v3.x*v3.x + v3.y*v3.y + v3.z*v3.z + v3.w*v3.w;
        #pragma unroll
        for (int o = 1; o < 8; o <<= 1) { s += __shfl_xor(s, o); q += __shfl_xor(q, o); }
        float mu = s * (1.0f / HH);
        float var = q * (1.0f / HH) - mu * mu;
        float rs = rsqrtf(var + 1e-5f);
        const float4* g4 = (const float4*)(gamma + sub * 16);
        const float4* b4 = (const float4*)(beta + sub * 16);
        float4 g0 = g4[0], g1 = g4[1], g2 = g4[2], g3 = g4[3];
        float4 e0 = b4[0], e1 = b4[1], e2 = b4[2], e3 = b4[3];
        float ov[16];
        ov[0]  = (v0.x - mu) * rs * g0.x + e0.x; ov[1]  = (v0.y - mu) * rs * g0.y + e0.y;
        ov[2]  = (v0.z - mu) * rs * g0.z + e0.z; ov[3]  = (v0.w - mu) * rs * g0.w + e0.w;
        ov[4]  = (v1.x - mu) * rs * g1.x + e1.x; ov[5]  = (v1.y - mu) * rs * g1.y + e1.y;
        ov[6]  = (v1.z - mu) * rs * g1.z + e1.z; ov[7]  = (v1.w - mu) * rs * g1.w + e1.w;
        ov[8]  = (v2.x - mu) * rs * g2.x + e2.x; ov[9]  = (v2.y - mu) * rs * g2.y + e2.y;
        ov[10] = (v2.z - mu) * rs * g2.z + e2.z; ov[11] = (v2.w - mu) * rs * g2.w + e2.w;
        ov[12] = (v3.x - mu) * rs * g3.x + e3.x; ov[13] = (v3.y - mu) * rs * g3.y + e3.y;
        ov[14] = (v3.z - mu) * rs * g3.z + e3.z; ov[15] = (v3.w - mu) * rs * g3.w + e3.w;
        if (gr < NN) {
            uint4 o0, o1;
            o0.x = pk2(ov[0], ov[1]);  o0.y = pk2(ov[2], ov[3]);
            o0.z = pk2(ov[4], ov[5]);  o0.w = pk2(ov[6], ov[7]);
            o1.x = pk2(ov[8], ov[9]);  o1.y = pk2(ov[10], ov[11]);
            o1.z = pk2(ov[12], ov[13]); o1.w = pk2(ov[14], ov[15]);
            uint4* op = (uint4*)&hout16[(size_t)gr * 128 + sub * 16];
            op[0] = o0; op[1] = o1;
        }
        // write LN'd f32 back to own slice (exclusive ownership, no race)
        #pragma unroll
        for (int j = 0; j < 16; ++j) Lr[j] = ov[j];
    }
    {
        __syncthreads();
        int g0 = gidx[0];
        int g1 = gidx[nrow - 1];
        int d = tid & 127, q = tid >> 7;
        for (int g = g0; g <= g1; ++g) {
            float s = 0.f, m = -INFINITY;
            bool any = false;
            for (int rr = q; rr < 64; rr += 4) {
                if (gidx[rr] == g) {
                    float v = Ln[rr * LNLD + d];
                    s += v; m = fmaxf(m, v);
                    any = true;
                }
            }
            if (any) {
                atomicAdd(&psum[g * HH + d], s);
                atomicMax(&pmaxu[g * HH + d], fenc(m));
            }
        }
    }
}

// ================================================================ pool finalize (64 x 128)
__global__ void poolout_kernel(const float* __restrict__ psum, const unsigned* __restrict__ pmaxu,
                               const int* __restrict__ batch, float* __restrict__ out) {
    int g = blockIdx.x;
    int d = threadIdx.x;
    int start, end;
    {
        int lo = 0, hi = NN;
        while (lo < hi) { int mid = (lo + hi) >> 1; if (batch[mid] < g) lo = mid + 1; else hi = mid; }
        start = lo;
        hi = NN;
        while (lo < hi) { int mid = (lo + hi) >> 1; if (batch[mid] < g + 1) lo = mid + 1; else hi = mid; }
        end = lo;
    }
    int cg = end - start;
    float s = psum[g * HH + d];
    float m = fdec(pmaxu[g * HH + d]);
    out[g * 2 * HH + d] = s / fmaxf((float)cg, 1.0f);
    out[g * 2 * HH + HH + d] = (cg > 0) ? m : 0.0f;
}

// ================================================================ launch
extern "C" void kernel_launch(void* const* d_in, const int* in_sizes, int n_in,
                              void* d_out, int out_size, void* d_ws, size_t ws_size,
                              hipStream_t stream) {
    const float* x     = (const float*)d_in[0];
    const int*   ast   = (const int*)d_in[1];
    const int*   batch = (const int*)d_in[2];
    const int*   ei    = (const int*)d_in[3];
    const float* emb   = (const float*)d_in[4];
    const float* W_in  = (const float*)d_in[5];
    const float* b_in  = (const float*)d_in[6];
    const float* W_l   = (const float*)d_in[7];
    const float* b_l   = (const float*)d_in[8];
    const float* W_r   = (const float*)d_in[9];
    const float* gamma = (const float*)d_in[10];
    const float* beta  = (const float*)d_in[11];
    float* out = (float*)d_out;

    const int M  = TT * NN;
    const int NB = (M + 1023) / 1024;

    char* p = (char*)d_ws;
    unsigned short* h16a = (unsigned short*)p;  p += (size_t)NN * HH * 2;   // 25.6 MB
    unsigned short* h16b = (unsigned short*)p;  p += (size_t)NN * HH * 2;   // 25.6 MB
    unsigned short* Wt16 = (unsigned short*)p;  p += (size_t)LL * WLSZ * 2;
    unsigned short* Wp_in = (unsigned short*)p; p += (size_t)32768 * 2;     // 64 KB
    float* blsum = (float*)p;                   p += LL * HH * 4;
    float* psum = (float*)p;                    p += (size_t)BB * HH * 4;
    unsigned* pmaxu = (unsigned*)p;             p += (size_t)BB * HH * 4;
    int* cnt    = (int*)p;                      p += (size_t)M * 4;
    int* offs   = (int*)p;                      p += (size_t)M * 4;
    int* cursor = (int*)p;                      p += (size_t)M * 4;
    int* csr    = (int*)p;                      p += (size_t)TT * EE * 4;
    int* bsums  = (int*)p;

    int conv_grid = (NN + 63) / 64;

    wprep_kernel<<<(LL * 4 * HH * HH + 255) / 256, 256, 0, stream>>>(
        W_l, W_r, b_l, W_in, Wt16, Wp_in, blsum, psum, pmaxu, cnt);
    input_proj_kernel<<<conv_grid, 512, 0, stream>>>(x, ast, emb, Wp_in, b_in, h16a, ei, cnt);
    scan1_kernel<<<NB, 256, 0, stream>>>(cnt, offs, bsums, M);
    scan2_kernel<<<1, 512, 0, stream>>>(bsums, NB);
    scan3_kernel<<<(M + 255) / 256, 256, 0, stream>>>(offs, bsums, cursor, M);
    fill_kernel<<<(TT * EE + 255) / 256, 256, 0, stream>>>(ei, cursor, csr);
    // layer 0
    conv0_kernel<<<conv_grid, 512, 0, stream>>>(h16a, Wt16, blsum, gamma, beta,
                                                offs, cnt, csr, h16b);
    // layer 1 + fused pool partials
    conv1_kernel<<<conv_grid, 512, 0, stream>>>(h16b, Wt16 + (size_t)WLSZ, blsum + HH,
                                                gamma + HH, beta + HH,
                                                offs, cnt, csr, h16a,
                                                batch, psum, pmaxu);
    poolout_kernel<<<BB, HH, 0, stream>>>(psum, pmaxu, batch, out);
}